// Round 11
// baseline (506.104 us; speedup 1.0000x reference)
//
#include <hip/hip_runtime.h>

// ---------------- types / helpers ----------------
typedef short bf8s __attribute__((ext_vector_type(8)));   // 8 bf16 (4 VGPRs)
typedef short s4   __attribute__((ext_vector_type(4)));   // 4 bf16 (8B store)
typedef float f32x4 __attribute__((ext_vector_type(4)));

#define MFMA16(a, b, c) __builtin_amdgcn_mfma_f32_16x16x32_bf16(a, b, c, 0, 0, 0)

constexpr int S_ = 512, HID_ = 128, B_ = 128, M_ = B_ * S_;

__device__ inline short f2bf(float f) {  // fp32 -> bf16 (RNE)
  unsigned u = __float_as_uint(f);
  u = (u + 0x7fffu + ((u >> 16) & 1u)) >> 16;
  return (short)u;
}
__device__ inline float bf2f(short s) {
  return __uint_as_float(((unsigned)(unsigned short)s) << 16);
}

__device__ inline float block_red1024(float v, float* red) {
  #pragma unroll
  for (int m = 32; m >= 1; m >>= 1) v += __shfl_xor(v, m);
  __syncthreads();
  if ((threadIdx.x & 63) == 0) red[threadIdx.x >> 6] = v;
  __syncthreads();
  float t = 0.f;
  #pragma unroll
  for (int i = 0; i < 16; ++i) t += red[i];
  return t;
}

// matrix table. doff layout (shorts):
//  per-layer QKV contiguous: l*49152 + {q:0,k:16384,v:32768}
//  ao: 98304 + l*16384 ; iw: 131072 + l*65536 ; fow: 262144 + l*65536 ; clf: 393216
__device__ inline void mat_info(int mat, const float* qw, const float* kw,
                                const float* vw, const float* aow, const float* iw,
                                const float* fw, const float* cw,
                                const float** src, int* n, int* doff) {
  if (mat < 6) {
    int l = mat / 3, which = mat % 3;
    const float* t[3] = {qw, kw, vw};
    *src = t[which] + l * 16384; *n = 16384; *doff = l * 49152 + which * 16384;
  } else if (mat < 8) {
    int l = mat - 6;
    *src = aow + l * 16384; *n = 16384; *doff = 98304 + l * 16384;
  } else if (mat < 10) {
    *src = iw + (mat - 8) * 65536; *n = 65536; *doff = 131072 + (mat - 8) * 65536;
  } else if (mat < 12) {
    *src = fw + (mat - 10) * 65536; *n = 65536; *doff = 262144 + (mat - 10) * 65536;
  } else {
    *src = cw; *n = 256; *doff = 393216;
  }
}

// ---------------- fused quant (blocks 0..12) + embed (blocks 13..) ----------------
__global__ __launch_bounds__(1024) void k_qe(const float* qw, const float* kw,
    const float* vw, const float* aow, const float* iw, const float* fw,
    const float* cw, short* WQ,
    const int* __restrict__ ids, const float* __restrict__ tok,
    const float* __restrict__ pos, const float* __restrict__ g,
    const float* __restrict__ bb, short* xb) {
  __shared__ float red[16];
  int tid = threadIdx.x;
  if (blockIdx.x < 13) {  // ---- ternary quantization ----
    const float* src; int n, doff;
    mat_info(blockIdx.x, qw, kw, vw, aow, iw, fw, cw, &src, &n, &doff);
    float s = 0.f;
    for (int i = tid; i < n; i += 1024) s += fabsf(src[i]);
    s = block_red1024(s, red);
    float delta = 0.7f * s / (float)n;
    float s2 = 0.f, c2 = 0.f;
    for (int i = tid; i < n; i += 1024) {
      float a = fabsf(src[i]);
      if (a > delta) { s2 += a; c2 += 1.f; }
    }
    s2 = block_red1024(s2, red);
    c2 = block_red1024(c2, red);
    float alpha = s2 / fmaxf(c2, 1.f);
    for (int i = tid; i < n; i += 1024) {
      float w = src[i];
      WQ[doff + i] = (fabsf(w) > delta) ? f2bf(w > 0.f ? alpha : -alpha) : (short)0;
    }
  } else {  // ---- embedding + LN ----
    int wave = tid >> 6, lane = tid & 63;
    int t = (blockIdx.x - 13) * 16 + wave;
    int s = t & (S_ - 1);
    int id = ids[t];
    float e0 = tok[(size_t)id * HID_ + lane] + pos[(size_t)s * HID_ + lane];
    float e1 = tok[(size_t)id * HID_ + 64 + lane] + pos[(size_t)s * HID_ + 64 + lane];
    float sum = e0 + e1, ssq = e0 * e0 + e1 * e1;
    #pragma unroll
    for (int m = 32; m >= 1; m >>= 1) {
      sum += __shfl_xor(sum, m);
      ssq += __shfl_xor(ssq, m);
    }
    float mean = sum / 128.f;
    float var = ssq / 128.f - mean * mean;
    float rs = rsqrtf(var + 1e-5f);
    size_t o = (size_t)t * HID_;
    xb[o + lane]      = f2bf((e0 - mean) * rs * g[lane] + bb[lane]);
    xb[o + 64 + lane] = f2bf((e1 - mean) * rs * g[64 + lane] + bb[64 + lane]);
  }
}

// ---------------- QKV linear -> MFMA-native packed layouts ----------------
// grid (M/64, 3); y=0: Q -> Qp[bh][s][64] scaled 0.125; y=1: K -> Kp[bh][s][64];
// y=2: V -> Vp[bh][64][S] (pre-transposed: PV B-frags become contiguous b128).
__global__ __launch_bounds__(256) void k_qkv(
    const short* __restrict__ A, const short* __restrict__ W,
    const float* __restrict__ b0, const float* __restrict__ b1,
    const float* __restrict__ b2, short* Qp, short* Kp, short* Vp) {
  __shared__ short Wl[128 * 136];
  int tid = threadIdx.x, lane = tid & 63, wave = tid >> 6;
  int row16 = lane & 15, quad = lane >> 4;
  int tok0 = blockIdx.x * 64 + wave * 16;
  int nbase = blockIdx.y * 128;

  const short* arow = A + (size_t)(tok0 + row16) * 128 + quad * 8;
  bf8s av[4];
  #pragma unroll
  for (int ki = 0; ki < 4; ++ki) av[ki] = *(const bf8s*)(arow + ki * 32);

  {
    int r = tid >> 1, half = tid & 1;
    const short* src = W + (size_t)(nbase + r) * 128 + half * 64;
    short* dst = &Wl[r * 136 + half * 64];
    #pragma unroll
    for (int j = 0; j < 8; ++j)
      *(bf8s*)(dst + j * 8) = *(const bf8s*)(src + j * 8);
  }
  __syncthreads();

  f32x4 acc[8] = {};
  #pragma unroll
  for (int ki = 0; ki < 4; ++ki)
    #pragma unroll
    for (int ot = 0; ot < 8; ++ot) {
      bf8s b = *(const bf8s*)(&Wl[(ot * 16 + row16) * 136 + ki * 32 + quad * 8]);
      acc[ot] = MFMA16(av[ki], b, acc[ot]);
    }

  const float* bp = (blockIdx.y == 0) ? b0 : ((blockIdx.y == 1) ? b1 : b2);
  float osc = (blockIdx.y == 0) ? 0.125f : 1.0f;  // fold 1/sqrt(64) into Q
  int bb2 = tok0 >> 9;             // batch (64-tok blocks never cross b)
  int s0 = (tok0 & 511) + quad * 4;  // sequence pos of r=0

  if (blockIdx.y < 2) {  // Q or K -> [bh][s][64]
    short* dst = (blockIdx.y == 0) ? Qp : Kp;
    #pragma unroll
    for (int ot = 0; ot < 8; ++ot) {
      int h = ot >> 2, d = (ot & 3) * 16 + row16;
      float bi = bp[ot * 16 + row16];
      short* p = dst + ((size_t)(bb2 * 2 + h) * S_) * 64 + d;
      #pragma unroll
      for (int r = 0; r < 4; ++r)
        p[(size_t)(s0 + r) * 64] = f2bf((acc[ot][r] + bi) * osc);
    }
  } else {  // V -> [bh][64][S], 4 s-consecutive packed in one 8B store
    #pragma unroll
    for (int ot = 0; ot < 8; ++ot) {
      int h = ot >> 2, d = (ot & 3) * 16 + row16;
      float bi = bp[ot * 16 + row16];
      s4 v;
      #pragma unroll
      for (int r = 0; r < 4; ++r) v[r] = f2bf(acc[ot][r] + bi);
      *(s4*)(Vp + (size_t)(bb2 * 2 + h) * 64 * S_ + (size_t)d * S_ + s0) = v;
    }
  }
}

// ---------------- flash attention: all operands global, ZERO barriers ----------------
// grid (4, 2, 128) = (qblock, h, b); block 256 (4 waves x 32 queries).
// K/V/Q pre-packed by k_qkv into MFMA-native layouts -> every frag is one b128
// global load (L2-hot). No LDS staging, no transpose, no __syncthreads; only the
// wave-private P stash. li row-sums kept per-lane, shuffle-reduced once at end.
// No-max softmax (Q pre-scaled; LN'd activations x ternary weights -> tiny scores).
__global__ __launch_bounds__(256) void k_attn(const short* __restrict__ Qp,
    const short* __restrict__ Kp, const short* __restrict__ Vp,
    short* __restrict__ O) {
  __shared__ short Pl[4][16 * 72];  // per-wave P stash (16 q x 64 k)

  int tid = threadIdx.x, lane = tid & 63, wave = tid >> 6;
  int row16 = lane & 15, quad = lane >> 4;
  int b = blockIdx.z, h = blockIdx.y, qb = blockIdx.x;
  size_t bh = (size_t)(b * 2 + h);
  const short* qbase = Qp + bh * S_ * 64;
  const short* kbase = Kp + bh * S_ * 64;
  const short* vbase = Vp + bh * 64 * S_;
  int q0 = qb * 128 + wave * 32;

  bf8s qa[2][2];
  #pragma unroll
  for (int qf = 0; qf < 2; ++qf) {
    const short* qrow = qbase + (size_t)(q0 + qf * 16 + row16) * 64 + quad * 8;
    qa[qf][0] = *(const bf8s*)(qrow);
    qa[qf][1] = *(const bf8s*)(qrow + 32);
  }

  float li[2][4] = {};
  f32x4 oacc[2][4] = {};
  short* myP = &Pl[wave][0];

  for (int kt = 0; kt < S_; kt += 64) {
    // K frags (shared by both q-frags) — direct global b128
    bf8s kf[4][2];
    #pragma unroll
    for (int ks = 0; ks < 4; ++ks) {
      const short* kp = kbase + (size_t)(kt + ks * 16 + row16) * 64 + quad * 8;
      kf[ks][0] = *(const bf8s*)(kp);
      kf[ks][1] = *(const bf8s*)(kp + 32);
    }
    // V frags (shared by both q-frags) — direct global b128 (pre-transposed)
    bf8s vf[4][2];
    #pragma unroll
    for (int dt = 0; dt < 4; ++dt) {
      const short* vp = vbase + (size_t)(dt * 16 + row16) * S_ + kt + quad * 8;
      vf[dt][0] = *(const bf8s*)(vp);
      vf[dt][1] = *(const bf8s*)(vp + 32);
    }

    f32x4 sc[2][4] = {};
    #pragma unroll
    for (int ks = 0; ks < 4; ++ks) {
      sc[0][ks] = MFMA16(qa[0][0], kf[ks][0], sc[0][ks]);
      sc[0][ks] = MFMA16(qa[0][1], kf[ks][1], sc[0][ks]);
      sc[1][ks] = MFMA16(qa[1][0], kf[ks][0], sc[1][ks]);
      sc[1][ks] = MFMA16(qa[1][1], kf[ks][1], sc[1][ks]);
    }

    #pragma unroll
    for (int qf = 0; qf < 2; ++qf) {
      #pragma unroll
      for (int ks = 0; ks < 4; ++ks)
        #pragma unroll
        for (int r = 0; r < 4; ++r) {
          float pv = __expf(sc[qf][ks][r]);
          li[qf][r] += pv;  // per-lane partial; cross-lane reduce deferred
          myP[(quad * 4 + r) * 72 + ks * 16 + row16] = f2bf(pv);
        }
      bf8s pa0 = *(const bf8s*)(&myP[row16 * 72 + quad * 8]);
      bf8s pa1 = *(const bf8s*)(&myP[row16 * 72 + 32 + quad * 8]);
      #pragma unroll
      for (int dt = 0; dt < 4; ++dt) {
        oacc[qf][dt] = MFMA16(pa0, vf[dt][0], oacc[qf][dt]);
        oacc[qf][dt] = MFMA16(pa1, vf[dt][1], oacc[qf][dt]);
      }
    }
  }

  // deferred li reduction (over the 16 lanes sharing a quad) + output
  #pragma unroll
  for (int qf = 0; qf < 2; ++qf) {
    float inv[4];
    #pragma unroll
    for (int r = 0; r < 4; ++r) {
      float t = li[qf][r];
      #pragma unroll
      for (int m = 1; m <= 8; m <<= 1) t += __shfl_xor(t, m);
      inv[r] = 1.f / t;
    }
    size_t trow = (size_t)(b * S_ + q0 + qf * 16 + quad * 4);
    #pragma unroll
    for (int dt = 0; dt < 4; ++dt)
      #pragma unroll
      for (int r = 0; r < 4; ++r)
        O[(trow + r) * HID_ + h * 64 + dt * 16 + row16] =
            f2bf(oacc[qf][dt][r] * inv[r]);
  }
}

// ---------------- fused AO + LN1 + FF1 + FF2 + LN2 ----------------
// 64-token blocks (grid 1024), 256 threads. Round-10 lesson: traffic ideal but
// barrier/stash-chain bound at 3 blocks/CU. Now: Wf B-frags read DIRECTLY from
// global (L2-resident, contiguous rows, not gated by any barrier -> prefetches
// during FF1). LDS = max(Wa 34816, Wi 17408 + stash 9216) = 34816 B -> 4 blocks/CU.
__global__ __launch_bounds__(256) void k_aoff(
    const short* __restrict__ cb, const short* __restrict__ Wa,
    const float* __restrict__ aob, const float* __restrict__ ln1g,
    const float* __restrict__ ln1b, const short* __restrict__ Wi,
    const short* __restrict__ Wf, const float* __restrict__ ib,
    const float* __restrict__ fb, const float* __restrict__ ln2g,
    const float* __restrict__ ln2b, short* xb) {
  __shared__ short SM[17408];  // 34816 B
  int tid = threadIdx.x, lane = tid & 63, wave = tid >> 6;
  int row16 = lane & 15, quad = lane >> 4;
  int tok0 = blockIdx.x * 64 + wave * 16;
  int m0 = tok0 + quad * 4;

  // ---- phase A: AO linear ----
  const short* arow = cb + (size_t)(tok0 + row16) * 128 + quad * 8;
  bf8s av[4];
  #pragma unroll
  for (int ki = 0; ki < 4; ++ki) av[ki] = *(const bf8s*)(arow + ki * 32);

  {  // stage Wa 128x128 (stride 136)
    int r = tid >> 1, half = tid & 1;
    const short* src = Wa + (size_t)r * 128 + half * 64;
    short* dst = &SM[r * 136 + half * 64];
    #pragma unroll
    for (int j = 0; j < 8; ++j)
      *(bf8s*)(dst + j * 8) = *(const bf8s*)(src + j * 8);
  }
  __syncthreads();

  f32x4 acc[8] = {};
  #pragma unroll
  for (int ki = 0; ki < 4; ++ki)
    #pragma unroll
    for (int ot = 0; ot < 8; ++ot) {
      bf8s b = *(const bf8s*)(&SM[(ot * 16 + row16) * 136 + ki * 32 + quad * 8]);
      acc[ot] = MFMA16(av[ki], b, acc[ot]);
    }

  // AO epilogue: bias + residual + LN1 -> x' kept in acc
  {
    float sum[4] = {}, ssq[4] = {};
    #pragma unroll
    for (int ot = 0; ot < 8; ++ot) {
      int col = ot * 16 + row16;
      float bi = aob[col];
      #pragma unroll
      for (int r = 0; r < 4; ++r) {
        float v = acc[ot][r] + bi + bf2f(xb[(size_t)(m0 + r) * HID_ + col]);
        acc[ot][r] = v;
        sum[r] += v; ssq[r] += v * v;
      }
    }
    #pragma unroll
    for (int m = 1; m <= 8; m <<= 1)
      #pragma unroll
      for (int r = 0; r < 4; ++r) {
        sum[r] += __shfl_xor(sum[r], m);
        ssq[r] += __shfl_xor(ssq[r], m);
      }
    float mean[4], rstd[4];
    #pragma unroll
    for (int r = 0; r < 4; ++r) {
      mean[r] = sum[r] / 128.f;
      float var = ssq[r] / 128.f - mean[r] * mean[r];
      rstd[r] = rsqrtf(var + 1e-5f);
    }
    #pragma unroll
    for (int ot = 0; ot < 8; ++ot) {
      int col = ot * 16 + row16;
      float gg = ln1g[col], bb2 = ln1b[col];
      #pragma unroll
      for (int r = 0; r < 4; ++r)
        acc[ot][r] = (acc[ot][r] - mean[r]) * rstd[r] * gg + bb2;  // x'
    }
  }

  // transpose x' -> A-frags through the (now-dead) Wa region; wave-private slice
  __syncthreads();  // all waves done reading Wa
  short* myX = &SM[wave * 4352];  // 16 rows x stride 136
  #pragma unroll
  for (int ot = 0; ot < 8; ++ot)
    #pragma unroll
    for (int r = 0; r < 4; ++r)
      myX[(quad * 4 + r) * 136 + ot * 16 + row16] = f2bf(acc[ot][r]);
  #pragma unroll
  for (int ki = 0; ki < 4; ++ki)
    av[ki] = *(const bf8s*)(myX + row16 * 136 + ki * 32 + quad * 8);

  // ---- phase B: FF over 8 inter-chunks; Wi staged, Wf global-direct ----
  short* SWi = SM;                         // 64 x 136
  short* mySt = SM + 8704 + wave * 1152;   // 16 x 72 per wave
  f32x4 acc2[8] = {};
  for (int c = 0; c < 8; ++c) {
    __syncthreads();  // c==0: protects myX reads; else: protects SWi reads
    {  // stage Wi chunk: 4 threads/row, 32 shorts
      int r = tid >> 2, q4 = tid & 3;
      const short* src = Wi + (size_t)(c * 64 + r) * HID_ + q4 * 32;
      short* dst = SWi + r * 136 + q4 * 32;
      #pragma unroll
      for (int j = 0; j < 4; ++j)
        *(bf8s*)(dst + j * 8) = *(const bf8s*)(src + j * 8);
    }
    __syncthreads();

    f32x4 hacc[4] = {};
    #pragma unroll
    for (int ki = 0; ki < 4; ++ki)
      #pragma unroll
      for (int ot = 0; ot < 4; ++ot) {
        bf8s b = *(const bf8s*)(SWi + (ot * 16 + row16) * 136 + ki * 32 + quad * 8);
        hacc[ot] = MFMA16(av[ki], b, hacc[ot]);
      }
    #pragma unroll
    for (int ot = 0; ot < 4; ++ot) {
      float bi = ib[c * 64 + ot * 16 + row16];
      #pragma unroll
      for (int r = 0; r < 4; ++r)
        mySt[(quad * 4 + r) * 72 + ot * 16 + row16] =
            f2bf(fmaxf(hacc[ot][r] + bi, 0.f));
    }
    bf8s ha0 = *(const bf8s*)(mySt + row16 * 72 + quad * 8);
    bf8s ha1 = *(const bf8s*)(mySt + row16 * 72 + 32 + quad * 8);
    #pragma unroll
    for (int ot = 0; ot < 8; ++ot) {  // Wf B-frags direct from global (L2)
      const short* wfp = Wf + (size_t)(ot * 16 + row16) * 512 + c * 64 + quad * 8;
      bf8s bA = *(const bf8s*)(wfp);
      bf8s bB = *(const bf8s*)(wfp + 32);
      acc2[ot] = MFMA16(ha0, bA, acc2[ot]);
      acc2[ot] = MFMA16(ha1, bB, acc2[ot]);
    }
  }

  // FF epilogue: + fb + x'(acc) + LN2 -> xb
  float sum[4] = {}, ssq[4] = {};
  #pragma unroll
  for (int ot = 0; ot < 8; ++ot) {
    int col = ot * 16 + row16;
    float bi = fb[col];
    #pragma unroll
    for (int r = 0; r < 4; ++r) {
      float v = acc2[ot][r] + bi + acc[ot][r];
      acc2[ot][r] = v;
      sum[r] += v; ssq[r] += v * v;
    }
  }
  #pragma unroll
  for (int m = 1; m <= 8; m <<= 1)
    #pragma unroll
    for (int r = 0; r < 4; ++r) {
      sum[r] += __shfl_xor(sum[r], m);
      ssq[r] += __shfl_xor(ssq[r], m);
    }
  float mean[4], rstd[4];
  #pragma unroll
  for (int r = 0; r < 4; ++r) {
    mean[r] = sum[r] / 128.f;
    float var = ssq[r] / 128.f - mean[r] * mean[r];
    rstd[r] = rsqrtf(var + 1e-5f);
  }
  #pragma unroll
  for (int ot = 0; ot < 8; ++ot) {
    int col = ot * 16 + row16;
    float gg = ln2g[col], bb2 = ln2b[col];
    #pragma unroll
    for (int r = 0; r < 4; ++r) {
      float v = (acc2[ot][r] - mean[r]) * rstd[r] * gg + bb2;
      xb[(size_t)(m0 + r) * HID_ + col] = f2bf(v);
    }
  }
}

// ---------------- classifier ----------------
__global__ __launch_bounds__(256) void k_clf(const short* __restrict__ xb,
    const short* __restrict__ Wc, const float* __restrict__ cbias, float* out) {
  int i = threadIdx.x;  // 256 = 128 batches x 2 classes
  int b = i >> 1, c = i & 1;
  float s = 0.f;
  for (int k = 0; k < HID_; ++k)
    s += bf2f(xb[(size_t)b * S_ * HID_ + k]) * bf2f(Wc[c * HID_ + k]);
  out[b * 2 + c] = s + cbias[c];
}

// ---------------- launcher ----------------
extern "C" void kernel_launch(void* const* d_in, const int* in_sizes, int n_in,
                              void* d_out, int out_size, void* d_ws, size_t ws_size,
                              hipStream_t stream) {
  const int*   ids     = (const int*)d_in[0];
  const float* tok_emb = (const float*)d_in[1];
  const float* pos_emb = (const float*)d_in[2];
  const float* ln_g    = (const float*)d_in[3];
  const float* ln_bb   = (const float*)d_in[4];
  const float* qw      = (const float*)d_in[5];
  const float* qbias   = (const float*)d_in[6];
  const float* kw      = (const float*)d_in[7];
  const float* kbias   = (const float*)d_in[8];
  const float* vw      = (const float*)d_in[9];
  const float* vbias   = (const float*)d_in[10];
  const float* aow     = (const float*)d_in[11];
  const float* aobias  = (const float*)d_in[12];
  const float* iw      = (const float*)d_in[13];
  const float* ibias   = (const float*)d_in[14];
  const float* fow     = (const float*)d_in[15];
  const float* fbias   = (const float*)d_in[16];
  const float* ln1g    = (const float*)d_in[17];
  const float* ln1b    = (const float*)d_in[18];
  const float* ln2g    = (const float*)d_in[19];
  const float* ln2b    = (const float*)d_in[20];
  const float* clfw    = (const float*)d_in[21];
  const float* clfb    = (const float*)d_in[22];

  char* ws = (char*)d_ws;
  short* WQ  = (short*)ws;                                   // 787 KB quantized weights
  short* xb  = (short*)(ws + 1048576);                       // bf16 trunk (16.8 MB)
  short* Qp  = (short*)(ws + 1048576 + 16777216);            // [bh][s][64] (16.8 MB)
  short* Kp  = Qp + (size_t)M_ * 64;                         // [bh][s][64] (16.8 MB)
  short* Vp  = Kp + (size_t)M_ * 64;                         // [bh][64][S] (16.8 MB)
  short* cb_ = Vp + (size_t)M_ * 64;                         // ctx [tok][128] (16.8 MB)

  k_qe<<<13 + M_ / 16, 1024, 0, stream>>>(qw, kw, vw, aow, iw, fow, clfw, WQ,
                                          ids, tok_emb, pos_emb, ln_g, ln_bb, xb);

  for (int l = 0; l < 2; ++l) {
    const short* Wqkv = WQ + (size_t)l * 49152;
    const short* Wa   = WQ + 98304 + (size_t)l * 16384;
    const short* Wi   = WQ + 131072 + (size_t)l * 65536;
    const short* Wf   = WQ + 262144 + (size_t)l * 65536;

    k_qkv<<<dim3(M_ / 64, 3), 256, 0, stream>>>(
        xb, Wqkv, qbias + l * HID_, kbias + l * HID_, vbias + l * HID_,
        Qp, Kp, Vp);
    k_attn<<<dim3(4, 2, B_), 256, 0, stream>>>(Qp, Kp, Vp, cb_);
    k_aoff<<<M_ / 64, 256, 0, stream>>>(
        cb_, Wa, aobias + l * HID_, ln1g + l * HID_, ln1b + l * HID_,
        Wi, Wf, ibias + l * 512, fbias + l * HID_,
        ln2g + l * HID_, ln2b + l * HID_, xb);
  }

  k_clf<<<1, 256, 0, stream>>>(xb, WQ + 393216, clfb, (float*)d_out);
}

// Round 12
// 355.405 us; speedup vs baseline: 1.4240x; 1.4240x over previous
//
#include <hip/hip_runtime.h>

// ---------------- types / helpers ----------------
typedef short bf8s __attribute__((ext_vector_type(8)));   // 8 bf16 (4 VGPRs)
typedef float f32x4 __attribute__((ext_vector_type(4)));

#define MFMA16(a, b, c) __builtin_amdgcn_mfma_f32_16x16x32_bf16(a, b, c, 0, 0, 0)

constexpr int S_ = 512, HID_ = 128, B_ = 128, M_ = B_ * S_;

__device__ inline short f2bf(float f) {  // fp32 -> bf16 (RNE)
  unsigned u = __float_as_uint(f);
  u = (u + 0x7fffu + ((u >> 16) & 1u)) >> 16;
  return (short)u;
}
__device__ inline float bf2f(short s) {
  return __uint_as_float(((unsigned)(unsigned short)s) << 16);
}

__device__ inline float block_red1024(float v, float* red) {
  #pragma unroll
  for (int m = 32; m >= 1; m >>= 1) v += __shfl_xor(v, m);
  __syncthreads();
  if ((threadIdx.x & 63) == 0) red[threadIdx.x >> 6] = v;
  __syncthreads();
  float t = 0.f;
  #pragma unroll
  for (int i = 0; i < 16; ++i) t += red[i];
  return t;
}

// matrix table. doff layout (shorts):
//  per-layer QKV contiguous: l*49152 + {q:0,k:16384,v:32768}
//  ao: 98304 + l*16384 ; iw: 131072 + l*65536 ; fow: 262144 + l*65536 ; clf: 393216
__device__ inline void mat_info(int mat, const float* qw, const float* kw,
                                const float* vw, const float* aow, const float* iw,
                                const float* fw, const float* cw,
                                const float** src, int* n, int* doff) {
  if (mat < 6) {
    int l = mat / 3, which = mat % 3;
    const float* t[3] = {qw, kw, vw};
    *src = t[which] + l * 16384; *n = 16384; *doff = l * 49152 + which * 16384;
  } else if (mat < 8) {
    int l = mat - 6;
    *src = aow + l * 16384; *n = 16384; *doff = 98304 + l * 16384;
  } else if (mat < 10) {
    *src = iw + (mat - 8) * 65536; *n = 65536; *doff = 131072 + (mat - 8) * 65536;
  } else if (mat < 12) {
    *src = fw + (mat - 10) * 65536; *n = 65536; *doff = 262144 + (mat - 10) * 65536;
  } else {
    *src = cw; *n = 256; *doff = 393216;
  }
}

// ---------------- fused quant (blocks 0..12) + embed (blocks 13..) ----------------
__global__ __launch_bounds__(1024) void k_qe(const float* qw, const float* kw,
    const float* vw, const float* aow, const float* iw, const float* fw,
    const float* cw, short* WQ,
    const int* __restrict__ ids, const float* __restrict__ tok,
    const float* __restrict__ pos, const float* __restrict__ g,
    const float* __restrict__ bb, short* xb) {
  __shared__ float red[16];
  int tid = threadIdx.x;
  if (blockIdx.x < 13) {  // ---- ternary quantization ----
    const float* src; int n, doff;
    mat_info(blockIdx.x, qw, kw, vw, aow, iw, fw, cw, &src, &n, &doff);
    float s = 0.f;
    for (int i = tid; i < n; i += 1024) s += fabsf(src[i]);
    s = block_red1024(s, red);
    float delta = 0.7f * s / (float)n;
    float s2 = 0.f, c2 = 0.f;
    for (int i = tid; i < n; i += 1024) {
      float a = fabsf(src[i]);
      if (a > delta) { s2 += a; c2 += 1.f; }
    }
    s2 = block_red1024(s2, red);
    c2 = block_red1024(c2, red);
    float alpha = s2 / fmaxf(c2, 1.f);
    for (int i = tid; i < n; i += 1024) {
      float w = src[i];
      WQ[doff + i] = (fabsf(w) > delta) ? f2bf(w > 0.f ? alpha : -alpha) : (short)0;
    }
  } else {  // ---- embedding + LN ----
    int wave = tid >> 6, lane = tid & 63;
    int t = (blockIdx.x - 13) * 16 + wave;
    int s = t & (S_ - 1);
    int id = ids[t];
    float e0 = tok[(size_t)id * HID_ + lane] + pos[(size_t)s * HID_ + lane];
    float e1 = tok[(size_t)id * HID_ + 64 + lane] + pos[(size_t)s * HID_ + 64 + lane];
    float sum = e0 + e1, ssq = e0 * e0 + e1 * e1;
    #pragma unroll
    for (int m = 32; m >= 1; m >>= 1) {
      sum += __shfl_xor(sum, m);
      ssq += __shfl_xor(ssq, m);
    }
    float mean = sum / 128.f;
    float var = ssq / 128.f - mean * mean;
    float rs = rsqrtf(var + 1e-5f);
    size_t o = (size_t)t * HID_;
    xb[o + lane]      = f2bf((e0 - mean) * rs * g[lane] + bb[lane]);
    xb[o + 64 + lane] = f2bf((e1 - mean) * rs * g[64 + lane] + bb[64 + lane]);
  }
}

// ---------------- QKV linear: 64-token blocks, A prefetched (round-10) ----------------
// grid (M/64, 3); y selects Q/K/V slice; Q output scaled 0.125 (fold 1/sqrt(64)).
// Writes [tok][384] coalesced (round-11 lesson: never trade coalesced stores
// for consumer layout without counting producer cost).
__global__ __launch_bounds__(256) void k_qkv(
    const short* __restrict__ A, const short* __restrict__ W,
    const float* __restrict__ b0, const float* __restrict__ b1,
    const float* __restrict__ b2, short* outb) {
  __shared__ short Wl[128 * 136];
  int tid = threadIdx.x, lane = tid & 63, wave = tid >> 6;
  int row16 = lane & 15, quad = lane >> 4;
  int tok0 = blockIdx.x * 64 + wave * 16;
  int nbase = blockIdx.y * 128;

  const short* arow = A + (size_t)(tok0 + row16) * 128 + quad * 8;
  bf8s av[4];
  #pragma unroll
  for (int ki = 0; ki < 4; ++ki) av[ki] = *(const bf8s*)(arow + ki * 32);

  {
    int r = tid >> 1, half = tid & 1;
    const short* src = W + (size_t)(nbase + r) * 128 + half * 64;
    short* dst = &Wl[r * 136 + half * 64];
    #pragma unroll
    for (int j = 0; j < 8; ++j)
      *(bf8s*)(dst + j * 8) = *(const bf8s*)(src + j * 8);
  }
  __syncthreads();

  f32x4 acc[8] = {};
  #pragma unroll
  for (int ki = 0; ki < 4; ++ki)
    #pragma unroll
    for (int ot = 0; ot < 8; ++ot) {
      bf8s b = *(const bf8s*)(&Wl[(ot * 16 + row16) * 136 + ki * 32 + quad * 8]);
      acc[ot] = MFMA16(av[ki], b, acc[ot]);
    }

  const float* bp = (blockIdx.y == 0) ? b0 : ((blockIdx.y == 1) ? b1 : b2);
  float osc = (blockIdx.y == 0) ? 0.125f : 1.0f;
  int m0 = tok0 + quad * 4;
  #pragma unroll
  for (int ot = 0; ot < 8; ++ot) {
    int col = ot * 16 + row16;
    float bi = bp[col];
    #pragma unroll
    for (int r = 0; r < 4; ++r) {
      float v = (acc[ot][r] + bi) * osc;
      outb[(size_t)(m0 + r) * 384 + nbase + col] = f2bf(v);
    }
  }
}

// ---------------- fused AO + LN1 + FF1 + FF2 + LN2, reg-double-buffered ----------------
// 64-token blocks, 256 threads. Round-10 base (traffic ideal, barrier-bound).
// New: (1) x' spilled bf16 to xb's own rows after LN1 (rows dead: residual
// consumed) freeing acc's 32 VGPRs; (2) next chunk's Wi+Wf prefetched into
// registers DURING current chunk's compute -> the post-barrier ds_write commits
// ready data, no global latency inside the barrier window (round-11 lesson:
// global-direct B-frags stall; staged + reg-prefetch amortizes).
// VGPR: av16 + wiR16 + wfR16 + acc2 32 = 80 persistent, ~112 peak < 128 cap.
__global__ __launch_bounds__(256) void k_aoff(
    const short* __restrict__ cb, const short* __restrict__ Wa,
    const float* __restrict__ aob, const float* __restrict__ ln1g,
    const float* __restrict__ ln1b, const short* __restrict__ Wi,
    const short* __restrict__ Wf, const float* __restrict__ ib,
    const float* __restrict__ fb, const float* __restrict__ ln2g,
    const float* __restrict__ ln2b, short* xb) {
  __shared__ short SM[22528];  // 45056 B
  int tid = threadIdx.x, lane = tid & 63, wave = tid >> 6;
  int row16 = lane & 15, quad = lane >> 4;
  int tok0 = blockIdx.x * 64 + wave * 16;
  int m0 = tok0 + quad * 4;

  // ---- phase A: AO linear ----
  const short* arow = cb + (size_t)(tok0 + row16) * 128 + quad * 8;
  bf8s av[4];
  #pragma unroll
  for (int ki = 0; ki < 4; ++ki) av[ki] = *(const bf8s*)(arow + ki * 32);

  {  // stage Wa 128x128 (stride 136)
    int r = tid >> 1, half = tid & 1;
    const short* src = Wa + (size_t)r * 128 + half * 64;
    short* dst = &SM[r * 136 + half * 64];
    #pragma unroll
    for (int j = 0; j < 8; ++j)
      *(bf8s*)(dst + j * 8) = *(const bf8s*)(src + j * 8);
  }
  __syncthreads();

  f32x4 acc[8] = {};
  #pragma unroll
  for (int ki = 0; ki < 4; ++ki)
    #pragma unroll
    for (int ot = 0; ot < 8; ++ot) {
      bf8s b = *(const bf8s*)(&SM[(ot * 16 + row16) * 136 + ki * 32 + quad * 8]);
      acc[ot] = MFMA16(av[ki], b, acc[ot]);
    }

  // prefetch chunk 0 of Wi/Wf into registers (overlaps AO epilogue)
  int rwi = tid >> 2, q4 = tid & 3;
  int rwf = tid >> 1, hwf = tid & 1;
  const short* wisrc = Wi + (size_t)rwi * HID_ + q4 * 32;
  const short* wfsrc = Wf + (size_t)rwf * 512 + hwf * 32;
  bf8s wiR[4], wfR[4];
  #pragma unroll
  for (int j = 0; j < 4; ++j) {
    wiR[j] = *(const bf8s*)(wisrc + j * 8);
    wfR[j] = *(const bf8s*)(wfsrc + j * 8);
  }

  // AO epilogue: bias + residual + LN1 -> x'
  {
    float sum[4] = {}, ssq[4] = {};
    #pragma unroll
    for (int ot = 0; ot < 8; ++ot) {
      int col = ot * 16 + row16;
      float bi = aob[col];
      #pragma unroll
      for (int r = 0; r < 4; ++r) {
        float v = acc[ot][r] + bi + bf2f(xb[(size_t)(m0 + r) * HID_ + col]);
        acc[ot][r] = v;
        sum[r] += v; ssq[r] += v * v;
      }
    }
    #pragma unroll
    for (int m = 1; m <= 8; m <<= 1)
      #pragma unroll
      for (int r = 0; r < 4; ++r) {
        sum[r] += __shfl_xor(sum[r], m);
        ssq[r] += __shfl_xor(ssq[r], m);
      }
    float mean[4], rstd[4];
    #pragma unroll
    for (int r = 0; r < 4; ++r) {
      mean[r] = sum[r] / 128.f;
      float var = ssq[r] / 128.f - mean[r] * mean[r];
      rstd[r] = rsqrtf(var + 1e-5f);
    }
    #pragma unroll
    for (int ot = 0; ot < 8; ++ot) {
      int col = ot * 16 + row16;
      float gg = ln1g[col], bb2 = ln1b[col];
      #pragma unroll
      for (int r = 0; r < 4; ++r)
        acc[ot][r] = (acc[ot][r] - mean[r]) * rstd[r] * gg + bb2;  // x'
    }
  }

  // spill x' (bf16) to xb's own rows (dead until our epilogue) -> frees acc regs
  #pragma unroll
  for (int ot = 0; ot < 8; ++ot) {
    int col = ot * 16 + row16;
    #pragma unroll
    for (int r = 0; r < 4; ++r)
      xb[(size_t)(m0 + r) * HID_ + col] = f2bf(acc[ot][r]);
  }

  // transpose x' -> A-frags through the (now-dead) Wa region; wave-private slice
  __syncthreads();  // all waves done reading Wa
  short* myX = &SM[wave * 4352];  // 16 rows x stride 136
  #pragma unroll
  for (int ot = 0; ot < 8; ++ot)
    #pragma unroll
    for (int r = 0; r < 4; ++r)
      myX[(quad * 4 + r) * 136 + ot * 16 + row16] = f2bf(acc[ot][r]);
  #pragma unroll
  for (int ki = 0; ki < 4; ++ki)
    av[ki] = *(const bf8s*)(myX + row16 * 136 + ki * 32 + quad * 8);

  // ---- phase B: FF over 8 inter-chunks (Wi+Wf staged, reg double-buffer) ----
  short* SWi = SM;                         // 64 x 136
  short* SWf = SM + 8704;                  // 128 x 72
  short* mySt = SM + 17920 + wave * 1152;  // 16 x 72 per wave
  f32x4 acc2[8] = {};
  for (int c = 0; c < 8; ++c) {
    __syncthreads();  // c==0: myX reads done; else: previous SWi/SWf reads done
    {  // commit prefetched chunk to LDS (data already in regs)
      short* dwi = SWi + rwi * 136 + q4 * 32;
      short* dwf = SWf + rwf * 72 + hwf * 32;
      #pragma unroll
      for (int j = 0; j < 4; ++j) {
        *(bf8s*)(dwi + j * 8) = wiR[j];
        *(bf8s*)(dwf + j * 8) = wfR[j];
      }
    }
    __syncthreads();
    if (c < 7) {  // prefetch next chunk; latency hides behind compute below
      const short* ws1 = wisrc + (size_t)(c + 1) * 64 * HID_;
      const short* ws2 = wfsrc + (c + 1) * 64;
      #pragma unroll
      for (int j = 0; j < 4; ++j) {
        wiR[j] = *(const bf8s*)(ws1 + j * 8);
        wfR[j] = *(const bf8s*)(ws2 + j * 8);
      }
    }

    f32x4 hacc[4] = {};
    #pragma unroll
    for (int ki = 0; ki < 4; ++ki)
      #pragma unroll
      for (int ot = 0; ot < 4; ++ot) {
        bf8s b = *(const bf8s*)(SWi + (ot * 16 + row16) * 136 + ki * 32 + quad * 8);
        hacc[ot] = MFMA16(av[ki], b, hacc[ot]);
      }
    #pragma unroll
    for (int ot = 0; ot < 4; ++ot) {
      float bi = ib[c * 64 + ot * 16 + row16];
      #pragma unroll
      for (int r = 0; r < 4; ++r)
        mySt[(quad * 4 + r) * 72 + ot * 16 + row16] =
            f2bf(fmaxf(hacc[ot][r] + bi, 0.f));
    }
    bf8s ha0 = *(const bf8s*)(mySt + row16 * 72 + quad * 8);
    bf8s ha1 = *(const bf8s*)(mySt + row16 * 72 + 32 + quad * 8);
    #pragma unroll
    for (int ot = 0; ot < 8; ++ot) {
      bf8s bA = *(const bf8s*)(SWf + (ot * 16 + row16) * 72 + quad * 8);
      bf8s bB = *(const bf8s*)(SWf + (ot * 16 + row16) * 72 + 32 + quad * 8);
      acc2[ot] = MFMA16(ha0, bA, acc2[ot]);
      acc2[ot] = MFMA16(ha1, bB, acc2[ot]);
    }
  }

  // FF epilogue: + fb + x'(from xb) + LN2 -> xb
  float sum[4] = {}, ssq[4] = {};
  #pragma unroll
  for (int ot = 0; ot < 8; ++ot) {
    int col = ot * 16 + row16;
    float bi = fb[col];
    #pragma unroll
    for (int r = 0; r < 4; ++r) {
      float v = acc2[ot][r] + bi + bf2f(xb[(size_t)(m0 + r) * HID_ + col]);
      acc2[ot][r] = v;
      sum[r] += v; ssq[r] += v * v;
    }
  }
  #pragma unroll
  for (int m = 1; m <= 8; m <<= 1)
    #pragma unroll
    for (int r = 0; r < 4; ++r) {
      sum[r] += __shfl_xor(sum[r], m);
      ssq[r] += __shfl_xor(ssq[r], m);
    }
  float mean[4], rstd[4];
  #pragma unroll
  for (int r = 0; r < 4; ++r) {
    mean[r] = sum[r] / 128.f;
    float var = ssq[r] / 128.f - mean[r] * mean[r];
    rstd[r] = rsqrtf(var + 1e-5f);
  }
  #pragma unroll
  for (int ot = 0; ot < 8; ++ot) {
    int col = ot * 16 + row16;
    float gg = ln2g[col], bb2 = ln2b[col];
    #pragma unroll
    for (int r = 0; r < 4; ++r) {
      float v = (acc2[ot][r] - mean[r]) * rstd[r] * gg + bb2;
      xb[(size_t)(m0 + r) * HID_ + col] = f2bf(v);
    }
  }
}

// ---------------- flash attention (round-10) + deferred li reduction ----------------
// grid = 512: blockIdx.x = (b<<2)|(h<<1)|qhalf. block = 512 (8 waves x 32 queries).
// LDS 36864 B -> 4 blocks/CU. Next stage's K/V reg-prefetched after the barrier.
// No-max softmax (Q pre-scaled; tiny scores). li kept as per-lane partials,
// shuffle-reduced ONCE in the epilogue (saves 12 shuffles/tile, removes the
// serializing reduce between exp and PV).
__global__ __launch_bounds__(512) void k_attn(const short* __restrict__ qkv,
                                              short* __restrict__ O) {
  __shared__ short Kl[64 * 72];     // 64 keys x 64 d, stride 72
  __shared__ short Vtl[64 * 72];    // 64 d x 64 keys, stride 72
  __shared__ short Pl[8][16 * 72];  // per-wave P stash (16 q x 64 k)

  int tid = threadIdx.x, lane = tid & 63, wave = tid >> 6;
  int row16 = lane & 15, quad = lane >> 4;
  int b = blockIdx.x >> 2, h = (blockIdx.x >> 1) & 1, qhalf = blockIdx.x & 1;
  const short* base  = qkv + (size_t)b * S_ * 384;
  const short* kbase = base + 128 + h * 64;
  const short* vbase = base + 256 + h * 64;
  int q0 = qhalf * 256 + wave * 32;

  bf8s qa[2][2];
  #pragma unroll
  for (int qf = 0; qf < 2; ++qf) {
    const short* qrow = base + h * 64 +
        (size_t)(q0 + qf * 16 + row16) * 384 + quad * 8;
    qa[qf][0] = *(const bf8s*)(qrow);
    qa[qf][1] = *(const bf8s*)(qrow + 32);
  }

  // staging thread->element maps
  int krow = tid >> 3, dgk = tid & 7;   // K: 64 rows x 8 d-groups
  int vkey = tid & 63, dgv = tid >> 6;  // V: 64 keys x 8 d-groups
  const short* kptr = kbase + (size_t)krow * 384 + dgk * 8;
  const short* vptr = vbase + (size_t)vkey * 384 + dgv * 8;
  bf8s kst = *(const bf8s*)(kptr);
  bf8s vst = *(const bf8s*)(vptr);

  float li[2][4] = {};
  f32x4 oacc[2][4] = {};
  short* myP = &Pl[wave][0];

  for (int kt0 = 0; kt0 < S_; kt0 += 64) {
    if (kt0) __syncthreads();
    *(bf8s*)(&Kl[krow * 72 + dgk * 8]) = kst;
    #pragma unroll
    for (int j = 0; j < 8; ++j) Vtl[(dgv * 8 + j) * 72 + vkey] = vst[j];
    __syncthreads();
    if (kt0 + 64 < S_) {  // prefetch next stage (overlaps compute below)
      kst = *(const bf8s*)(kptr + (size_t)(kt0 + 64) * 384);
      vst = *(const bf8s*)(vptr + (size_t)(kt0 + 64) * 384);
    }

    f32x4 sc[2][4] = {};
    #pragma unroll
    for (int ks = 0; ks < 4; ++ks) {
      const short* kp = &Kl[(ks * 16 + row16) * 72 + quad * 8];
      bf8s k0 = *(const bf8s*)(kp);
      bf8s k1 = *(const bf8s*)(kp + 32);
      sc[0][ks] = MFMA16(qa[0][0], k0, sc[0][ks]);
      sc[0][ks] = MFMA16(qa[0][1], k1, sc[0][ks]);
      sc[1][ks] = MFMA16(qa[1][0], k0, sc[1][ks]);
      sc[1][ks] = MFMA16(qa[1][1], k1, sc[1][ks]);
    }

    #pragma unroll
    for (int qf = 0; qf < 2; ++qf) {
      #pragma unroll
      for (int ks = 0; ks < 4; ++ks)
        #pragma unroll
        for (int r = 0; r < 4; ++r) {
          float pv = __expf(sc[qf][ks][r]);
          li[qf][r] += pv;  // per-lane partial; cross-lane reduce deferred
          myP[(quad * 4 + r) * 72 + ks * 16 + row16] = f2bf(pv);
        }
      bf8s pa0 = *(const bf8s*)(&myP[row16 * 72 + quad * 8]);
      bf8s pa1 = *(const bf8s*)(&myP[row16 * 72 + 32 + quad * 8]);
      #pragma unroll
      for (int dt = 0; dt < 4; ++dt) {
        const short* vp = &Vtl[(dt * 16 + row16) * 72 + quad * 8];
        bf8s v0 = *(const bf8s*)(vp);
        bf8s v1 = *(const bf8s*)(vp + 32);
        oacc[qf][dt] = MFMA16(pa0, v0, oacc[qf][dt]);
        oacc[qf][dt] = MFMA16(pa1, v1, oacc[qf][dt]);
      }
    }
  }

  #pragma unroll
  for (int qf = 0; qf < 2; ++qf) {
    float inv[4];
    #pragma unroll
    for (int r = 0; r < 4; ++r) {
      float t = li[qf][r];
      #pragma unroll
      for (int m = 1; m <= 8; m <<= 1) t += __shfl_xor(t, m);
      inv[r] = 1.f / t;
    }
    size_t trow = (size_t)(b * S_ + q0 + qf * 16 + quad * 4);
    #pragma unroll
    for (int dt = 0; dt < 4; ++dt)
      #pragma unroll
      for (int r = 0; r < 4; ++r)
        O[(trow + r) * HID_ + h * 64 + dt * 16 + row16] =
            f2bf(oacc[qf][dt][r] * inv[r]);
  }
}

// ---------------- classifier ----------------
__global__ __launch_bounds__(256) void k_clf(const short* __restrict__ xb,
    const short* __restrict__ Wc, const float* __restrict__ cbias, float* out) {
  int i = threadIdx.x;  // 256 = 128 batches x 2 classes
  int b = i >> 1, c = i & 1;
  float s = 0.f;
  for (int k = 0; k < HID_; ++k)
    s += bf2f(xb[(size_t)b * S_ * HID_ + k]) * bf2f(Wc[c * HID_ + k]);
  out[b * 2 + c] = s + cbias[c];
}

// ---------------- launcher ----------------
extern "C" void kernel_launch(void* const* d_in, const int* in_sizes, int n_in,
                              void* d_out, int out_size, void* d_ws, size_t ws_size,
                              hipStream_t stream) {
  const int*   ids     = (const int*)d_in[0];
  const float* tok_emb = (const float*)d_in[1];
  const float* pos_emb = (const float*)d_in[2];
  const float* ln_g    = (const float*)d_in[3];
  const float* ln_bb   = (const float*)d_in[4];
  const float* qw      = (const float*)d_in[5];
  const float* qbias   = (const float*)d_in[6];
  const float* kw      = (const float*)d_in[7];
  const float* kbias   = (const float*)d_in[8];
  const float* vw      = (const float*)d_in[9];
  const float* vbias   = (const float*)d_in[10];
  const float* aow     = (const float*)d_in[11];
  const float* aobias  = (const float*)d_in[12];
  const float* iw      = (const float*)d_in[13];
  const float* ibias   = (const float*)d_in[14];
  const float* fow     = (const float*)d_in[15];
  const float* fbias   = (const float*)d_in[16];
  const float* ln1g    = (const float*)d_in[17];
  const float* ln1b    = (const float*)d_in[18];
  const float* ln2g    = (const float*)d_in[19];
  const float* ln2b    = (const float*)d_in[20];
  const float* clfw    = (const float*)d_in[21];
  const float* clfb    = (const float*)d_in[22];

  char* ws = (char*)d_ws;
  short* WQ  = (short*)ws;                                   // 787 KB quantized weights
  short* xb  = (short*)(ws + 1048576);                       // bf16 trunk (16.8 MB)
  short* qkv = (short*)(ws + 1048576 + 16777216);            // [tok][384] (50.3 MB)
  short* cb_ = qkv + (size_t)M_ * 384;                       // ctx [tok][128] (16.8 MB)

  k_qe<<<13 + M_ / 16, 1024, 0, stream>>>(qw, kw, vw, aow, iw, fow, clfw, WQ,
                                          ids, tok_emb, pos_emb, ln_g, ln_bb, xb);

  for (int l = 0; l < 2; ++l) {
    const short* Wqkv = WQ + (size_t)l * 49152;
    const short* Wa   = WQ + 98304 + (size_t)l * 16384;
    const short* Wi   = WQ + 131072 + (size_t)l * 65536;
    const short* Wf   = WQ + 262144 + (size_t)l * 65536;

    k_qkv<<<dim3(M_ / 64, 3), 256, 0, stream>>>(
        xb, Wqkv, qbias + l * HID_, kbias + l * HID_, vbias + l * HID_, qkv);
    k_attn<<<512, 512, 0, stream>>>(qkv, cb_);
    k_aoff<<<M_ / 64, 256, 0, stream>>>(
        cb_, Wa, aobias + l * HID_, ln1g + l * HID_, ln1b + l * HID_,
        Wi, Wf, ibias + l * 512, fbias + l * HID_,
        ln2g + l * HID_, ln2b + l * HID_, xb);
  }

  k_clf<<<1, 256, 0, stream>>>(xb, WQ + 393216, clfb, (float*)d_out);
}

// Round 13
// 328.699 us; speedup vs baseline: 1.5397x; 1.0812x over previous
//
#include <hip/hip_runtime.h>

// ---------------- types / helpers ----------------
typedef short bf8s __attribute__((ext_vector_type(8)));   // 8 bf16 (4 VGPRs)
typedef float f32x4 __attribute__((ext_vector_type(4)));

#define MFMA16(a, b, c) __builtin_amdgcn_mfma_f32_16x16x32_bf16(a, b, c, 0, 0, 0)

constexpr int S_ = 512, HID_ = 128, B_ = 128, M_ = B_ * S_;

__device__ inline short f2bf(float f) {  // fp32 -> bf16 (RNE)
  unsigned u = __float_as_uint(f);
  u = (u + 0x7fffu + ((u >> 16) & 1u)) >> 16;
  return (short)u;
}
__device__ inline float bf2f(short s) {
  return __uint_as_float(((unsigned)(unsigned short)s) << 16);
}

__device__ inline float block_red1024(float v, float* red) {
  #pragma unroll
  for (int m = 32; m >= 1; m >>= 1) v += __shfl_xor(v, m);
  __syncthreads();
  if ((threadIdx.x & 63) == 0) red[threadIdx.x >> 6] = v;
  __syncthreads();
  float t = 0.f;
  #pragma unroll
  for (int i = 0; i < 16; ++i) t += red[i];
  return t;
}

// matrix table. doff layout (shorts):
//  per-layer QKV contiguous: l*49152 + {q:0,k:16384,v:32768}
//  ao: 98304 + l*16384 ; iw: 131072 + l*65536 ; fow: 262144 + l*65536 ; clf: 393216
__device__ inline void mat_info(int mat, const float* qw, const float* kw,
                                const float* vw, const float* aow, const float* iw,
                                const float* fw, const float* cw,
                                const float** src, int* n, int* doff) {
  if (mat < 6) {
    int l = mat / 3, which = mat % 3;
    const float* t[3] = {qw, kw, vw};
    *src = t[which] + l * 16384; *n = 16384; *doff = l * 49152 + which * 16384;
  } else if (mat < 8) {
    int l = mat - 6;
    *src = aow + l * 16384; *n = 16384; *doff = 98304 + l * 16384;
  } else if (mat < 10) {
    *src = iw + (mat - 8) * 65536; *n = 65536; *doff = 131072 + (mat - 8) * 65536;
  } else if (mat < 12) {
    *src = fw + (mat - 10) * 65536; *n = 65536; *doff = 262144 + (mat - 10) * 65536;
  } else {
    *src = cw; *n = 256; *doff = 393216;
  }
}

// ---------------- fused quant (blocks 0..12) + embed (blocks 13..) ----------------
__global__ __launch_bounds__(1024) void k_qe(const float* qw, const float* kw,
    const float* vw, const float* aow, const float* iw, const float* fw,
    const float* cw, short* WQ,
    const int* __restrict__ ids, const float* __restrict__ tok,
    const float* __restrict__ pos, const float* __restrict__ g,
    const float* __restrict__ bb, short* xb) {
  __shared__ float red[16];
  int tid = threadIdx.x;
  if (blockIdx.x < 13) {  // ---- ternary quantization ----
    const float* src; int n, doff;
    mat_info(blockIdx.x, qw, kw, vw, aow, iw, fw, cw, &src, &n, &doff);
    float s = 0.f;
    for (int i = tid; i < n; i += 1024) s += fabsf(src[i]);
    s = block_red1024(s, red);
    float delta = 0.7f * s / (float)n;
    float s2 = 0.f, c2 = 0.f;
    for (int i = tid; i < n; i += 1024) {
      float a = fabsf(src[i]);
      if (a > delta) { s2 += a; c2 += 1.f; }
    }
    s2 = block_red1024(s2, red);
    c2 = block_red1024(c2, red);
    float alpha = s2 / fmaxf(c2, 1.f);
    for (int i = tid; i < n; i += 1024) {
      float w = src[i];
      WQ[doff + i] = (fabsf(w) > delta) ? f2bf(w > 0.f ? alpha : -alpha) : (short)0;
    }
  } else {  // ---- embedding + LN ----
    int wave = tid >> 6, lane = tid & 63;
    int t = (blockIdx.x - 13) * 16 + wave;
    int s = t & (S_ - 1);
    int id = ids[t];
    float e0 = tok[(size_t)id * HID_ + lane] + pos[(size_t)s * HID_ + lane];
    float e1 = tok[(size_t)id * HID_ + 64 + lane] + pos[(size_t)s * HID_ + 64 + lane];
    float sum = e0 + e1, ssq = e0 * e0 + e1 * e1;
    #pragma unroll
    for (int m = 32; m >= 1; m >>= 1) {
      sum += __shfl_xor(sum, m);
      ssq += __shfl_xor(ssq, m);
    }
    float mean = sum / 128.f;
    float var = ssq / 128.f - mean * mean;
    float rs = rsqrtf(var + 1e-5f);
    size_t o = (size_t)t * HID_;
    xb[o + lane]      = f2bf((e0 - mean) * rs * g[lane] + bb[lane]);
    xb[o + 64 + lane] = f2bf((e1 - mean) * rs * g[64 + lane] + bb[64 + lane]);
  }
}

// ---------------- QKV linear (layer 0 only): 64-tok blocks, stride-144 LDS ----------------
__global__ __launch_bounds__(256) void k_qkv(
    const short* __restrict__ A, const short* __restrict__ W,
    const float* __restrict__ b0, const float* __restrict__ b1,
    const float* __restrict__ b2, short* outb) {
  __shared__ short Wl[128 * 144];  // 144 shorts = 72 words (8 mod 32): 4-way not 8-way
  int tid = threadIdx.x, lane = tid & 63, wave = tid >> 6;
  int row16 = lane & 15, quad = lane >> 4;
  int tok0 = blockIdx.x * 64 + wave * 16;
  int nbase = blockIdx.y * 128;

  const short* arow = A + (size_t)(tok0 + row16) * 128 + quad * 8;
  bf8s av[4];
  #pragma unroll
  for (int ki = 0; ki < 4; ++ki) av[ki] = *(const bf8s*)(arow + ki * 32);

  {
    int r = tid >> 1, half = tid & 1;
    const short* src = W + (size_t)(nbase + r) * 128 + half * 64;
    short* dst = &Wl[r * 144 + half * 64];
    #pragma unroll
    for (int j = 0; j < 8; ++j)
      *(bf8s*)(dst + j * 8) = *(const bf8s*)(src + j * 8);
  }
  __syncthreads();

  f32x4 acc[8] = {};
  #pragma unroll
  for (int ki = 0; ki < 4; ++ki)
    #pragma unroll
    for (int ot = 0; ot < 8; ++ot) {
      bf8s b = *(const bf8s*)(&Wl[(ot * 16 + row16) * 144 + ki * 32 + quad * 8]);
      acc[ot] = MFMA16(av[ki], b, acc[ot]);
    }

  const float* bp = (blockIdx.y == 0) ? b0 : ((blockIdx.y == 1) ? b1 : b2);
  float osc = (blockIdx.y == 0) ? 0.125f : 1.0f;  // fold 1/sqrt(64) into Q
  int m0 = tok0 + quad * 4;
  #pragma unroll
  for (int ot = 0; ot < 8; ++ot) {
    int col = ot * 16 + row16;
    float bi = bp[col];
    #pragma unroll
    for (int r = 0; r < 4; ++r) {
      float v = (acc[ot][r] + bi) * osc;
      outb[(size_t)(m0 + r) * 384 + nbase + col] = f2bf(v);
    }
  }
}

// ---------------- fused AO+LN1+FF1+FF2+LN2 [+ next-layer QKV] ----------------
// 512 threads / 128 tokens (grid 512 = exactly 2 blocks/CU, no tail).
// Round-12 lesson: reg-prefetch alone didn't help (chain-bound at 12 waves/CU);
// now barriers amortize over 2x MFMA (Wi/Wf staged once per 128 tok) and
// 16 waves/CU overlap the FF1->stash->FF2 chains. LDS strides 144/80
// (72/40 words, 8 mod 32) halve bank-conflict multiplicity vs 136/72.
// DOQKV: x'' (post-LN2, in regs) -> transpose -> 3 chunks of next-layer QKV,
// removing that k_qkv dispatch + xb re-read.
// LDS: phase A Wa 128x144=18432sh | FF: SWi 64x144=9216 + SWf 128x80=10240 +
// stash 8x16x80=10240 = 29696sh (59392 B < 64 KB static) -> 2 blocks/CU.
template <int DOQKV>
__global__ __launch_bounds__(512) void k_aoff(
    const short* __restrict__ cb, const short* __restrict__ Wa,
    const float* __restrict__ aob, const float* __restrict__ ln1g,
    const float* __restrict__ ln1b, const short* __restrict__ Wi,
    const short* __restrict__ Wf, const float* __restrict__ ib,
    const float* __restrict__ fb, const float* __restrict__ ln2g,
    const float* __restrict__ ln2b, short* xb,
    const short* __restrict__ Wqkv2, const float* __restrict__ qb2,
    const float* __restrict__ kb2, const float* __restrict__ vb2,
    short* qkvout) {
  __shared__ short SM[29696];
  int tid = threadIdx.x, lane = tid & 63, wave = tid >> 6;
  int row16 = lane & 15, quad = lane >> 4;
  int tok0 = blockIdx.x * 128 + wave * 16;
  int m0 = tok0 + quad * 4;

  // ---- phase A: AO linear ----
  const short* arow = cb + (size_t)(tok0 + row16) * 128 + quad * 8;
  bf8s av[4];
  #pragma unroll
  for (int ki = 0; ki < 4; ++ki) av[ki] = *(const bf8s*)(arow + ki * 32);

  {  // stage Wa 128x128 (stride 144): 4 threads/row, 32 shorts each
    int r = tid >> 2, q4 = tid & 3;
    const short* src = Wa + (size_t)r * 128 + q4 * 32;
    short* dst = &SM[r * 144 + q4 * 32];
    #pragma unroll
    for (int j = 0; j < 4; ++j)
      *(bf8s*)(dst + j * 8) = *(const bf8s*)(src + j * 8);
  }
  __syncthreads();

  f32x4 acc[8] = {};
  #pragma unroll
  for (int ki = 0; ki < 4; ++ki)
    #pragma unroll
    for (int ot = 0; ot < 8; ++ot) {
      bf8s b = *(const bf8s*)(&SM[(ot * 16 + row16) * 144 + ki * 32 + quad * 8]);
      acc[ot] = MFMA16(av[ki], b, acc[ot]);
    }

  // prefetch FF chunk 0 into registers (overlaps AO epilogue)
  int rwi = tid >> 3, q8 = tid & 7;   // Wi: 64 rows x 8 groups of 16 shorts
  int rwf = tid >> 2, qf4 = tid & 3;  // Wf: 128 rows x 4 groups of 16 shorts
  const short* wisrc = Wi + (size_t)rwi * HID_ + q8 * 16;
  const short* wfsrc = Wf + (size_t)rwf * 512 + qf4 * 16;
  bf8s wiR[2], wfR[2];
  #pragma unroll
  for (int j = 0; j < 2; ++j) {
    wiR[j] = *(const bf8s*)(wisrc + j * 8);
    wfR[j] = *(const bf8s*)(wfsrc + j * 8);
  }

  // AO epilogue: bias + residual + LN1 -> x'
  {
    float sum[4] = {}, ssq[4] = {};
    #pragma unroll
    for (int ot = 0; ot < 8; ++ot) {
      int col = ot * 16 + row16;
      float bi = aob[col];
      #pragma unroll
      for (int r = 0; r < 4; ++r) {
        float v = acc[ot][r] + bi + bf2f(xb[(size_t)(m0 + r) * HID_ + col]);
        acc[ot][r] = v;
        sum[r] += v; ssq[r] += v * v;
      }
    }
    #pragma unroll
    for (int m = 1; m <= 8; m <<= 1)
      #pragma unroll
      for (int r = 0; r < 4; ++r) {
        sum[r] += __shfl_xor(sum[r], m);
        ssq[r] += __shfl_xor(ssq[r], m);
      }
    float mean[4], rstd[4];
    #pragma unroll
    for (int r = 0; r < 4; ++r) {
      mean[r] = sum[r] / 128.f;
      float var = ssq[r] / 128.f - mean[r] * mean[r];
      rstd[r] = rsqrtf(var + 1e-5f);
    }
    #pragma unroll
    for (int ot = 0; ot < 8; ++ot) {
      int col = ot * 16 + row16;
      float gg = ln1g[col], bb2 = ln1b[col];
      #pragma unroll
      for (int r = 0; r < 4; ++r)
        acc[ot][r] = (acc[ot][r] - mean[r]) * rstd[r] * gg + bb2;  // x'
    }
  }

  // spill x' (bf16) to xb's own rows (dead until FF epilogue) -> frees acc regs
  #pragma unroll
  for (int ot = 0; ot < 8; ++ot) {
    int col = ot * 16 + row16;
    #pragma unroll
    for (int r = 0; r < 4; ++r)
      xb[(size_t)(m0 + r) * HID_ + col] = f2bf(acc[ot][r]);
  }

  // transpose x' -> A-frags through the (dead) Wa region; wave-private slice
  __syncthreads();
  {
    short* myX = &SM[wave * 2304];  // 16 rows x stride 144
    #pragma unroll
    for (int ot = 0; ot < 8; ++ot)
      #pragma unroll
      for (int r = 0; r < 4; ++r)
        myX[(quad * 4 + r) * 144 + ot * 16 + row16] = f2bf(acc[ot][r]);
    #pragma unroll
    for (int ki = 0; ki < 4; ++ki)
      av[ki] = *(const bf8s*)(myX + row16 * 144 + ki * 32 + quad * 8);
  }

  // ---- phase B: FF over 8 inter-chunks (staged, reg double-buffer) ----
  short* SWi = SM;                         // 64 x 144
  short* SWf = SM + 9216;                  // 128 x 80
  short* mySt = SM + 19456 + wave * 1280;  // 16 x 80 per wave
  f32x4 acc2[8] = {};
  for (int c = 0; c < 8; ++c) {
    __syncthreads();  // c==0: myX reads done; else: previous SWi/SWf reads done
    {  // commit prefetched chunk (data already in regs)
      short* dwi = SWi + rwi * 144 + q8 * 16;
      short* dwf = SWf + rwf * 80 + qf4 * 16;
      #pragma unroll
      for (int j = 0; j < 2; ++j) {
        *(bf8s*)(dwi + j * 8) = wiR[j];
        *(bf8s*)(dwf + j * 8) = wfR[j];
      }
    }
    __syncthreads();
    if (c < 7) {  // prefetch next chunk; hides behind compute below
      const short* ws1 = wisrc + (size_t)(c + 1) * 64 * HID_;
      const short* ws2 = wfsrc + (c + 1) * 64;
      #pragma unroll
      for (int j = 0; j < 2; ++j) {
        wiR[j] = *(const bf8s*)(ws1 + j * 8);
        wfR[j] = *(const bf8s*)(ws2 + j * 8);
      }
    }

    f32x4 hacc[4] = {};
    #pragma unroll
    for (int ki = 0; ki < 4; ++ki)
      #pragma unroll
      for (int ot = 0; ot < 4; ++ot) {
        bf8s b = *(const bf8s*)(SWi + (ot * 16 + row16) * 144 + ki * 32 + quad * 8);
        hacc[ot] = MFMA16(av[ki], b, hacc[ot]);
      }
    #pragma unroll
    for (int ot = 0; ot < 4; ++ot) {
      float bi = ib[c * 64 + ot * 16 + row16];
      #pragma unroll
      for (int r = 0; r < 4; ++r)
        mySt[(quad * 4 + r) * 80 + ot * 16 + row16] =
            f2bf(fmaxf(hacc[ot][r] + bi, 0.f));
    }
    bf8s ha0 = *(const bf8s*)(mySt + row16 * 80 + quad * 8);
    bf8s ha1 = *(const bf8s*)(mySt + row16 * 80 + 32 + quad * 8);
    #pragma unroll
    for (int ot = 0; ot < 8; ++ot) {
      bf8s bA = *(const bf8s*)(SWf + (ot * 16 + row16) * 80 + quad * 8);
      bf8s bB = *(const bf8s*)(SWf + (ot * 16 + row16) * 80 + 32 + quad * 8);
      acc2[ot] = MFMA16(ha0, bA, acc2[ot]);
      acc2[ot] = MFMA16(ha1, bB, acc2[ot]);
    }
  }

  // FF epilogue: + fb + x'(from xb) + LN2 -> x'' in acc2; write xb
  {
    float sum[4] = {}, ssq[4] = {};
    #pragma unroll
    for (int ot = 0; ot < 8; ++ot) {
      int col = ot * 16 + row16;
      float bi = fb[col];
      #pragma unroll
      for (int r = 0; r < 4; ++r) {
        float v = acc2[ot][r] + bi + bf2f(xb[(size_t)(m0 + r) * HID_ + col]);
        acc2[ot][r] = v;
        sum[r] += v; ssq[r] += v * v;
      }
    }
    #pragma unroll
    for (int m = 1; m <= 8; m <<= 1)
      #pragma unroll
      for (int r = 0; r < 4; ++r) {
        sum[r] += __shfl_xor(sum[r], m);
        ssq[r] += __shfl_xor(ssq[r], m);
      }
    float mean[4], rstd[4];
    #pragma unroll
    for (int r = 0; r < 4; ++r) {
      mean[r] = sum[r] / 128.f;
      float var = ssq[r] / 128.f - mean[r] * mean[r];
      rstd[r] = rsqrtf(var + 1e-5f);
    }
    #pragma unroll
    for (int ot = 0; ot < 8; ++ot) {
      int col = ot * 16 + row16;
      float gg = ln2g[col], bb2 = ln2b[col];
      #pragma unroll
      for (int r = 0; r < 4; ++r) {
        float v = (acc2[ot][r] - mean[r]) * rstd[r] * gg + bb2;
        acc2[ot][r] = v;
        xb[(size_t)(m0 + r) * HID_ + col] = f2bf(v);
      }
    }
  }

  if (DOQKV) {
    // ---- tail: next-layer QKV for our own 128 tokens ----
    __syncthreads();  // all FF LDS reads done
    bf8s av2[4];
    {
      short* myX = &SM[wave * 2304];  // 16 rows x stride 144
      #pragma unroll
      for (int ot = 0; ot < 8; ++ot)
        #pragma unroll
        for (int r = 0; r < 4; ++r)
          myX[(quad * 4 + r) * 144 + ot * 16 + row16] = f2bf(acc2[ot][r]);
      #pragma unroll
      for (int ki = 0; ki < 4; ++ki)
        av2[ki] = *(const bf8s*)(myX + row16 * 144 + ki * 32 + quad * 8);
    }
    for (int c3 = 0; c3 < 3; ++c3) {
      __syncthreads();  // protects myX (c3==0) / previous chunk reads
      {  // stage Wqkv chunk 128x128 (stride 144): 4 threads/row
        int r = tid >> 2, q4 = tid & 3;
        const short* src = Wqkv2 + (size_t)(c3 * 128 + r) * 128 + q4 * 32;
        short* dst = &SM[r * 144 + q4 * 32];
        #pragma unroll
        for (int j = 0; j < 4; ++j)
          *(bf8s*)(dst + j * 8) = *(const bf8s*)(src + j * 8);
      }
      __syncthreads();
      f32x4 acc3[8] = {};
      #pragma unroll
      for (int ki = 0; ki < 4; ++ki)
        #pragma unroll
        for (int ot = 0; ot < 8; ++ot) {
          bf8s b = *(const bf8s*)(&SM[(ot * 16 + row16) * 144 + ki * 32 + quad * 8]);
          acc3[ot] = MFMA16(av2[ki], b, acc3[ot]);
        }
      const float* bp = (c3 == 0) ? qb2 : ((c3 == 1) ? kb2 : vb2);
      float osc = (c3 == 0) ? 0.125f : 1.0f;
      #pragma unroll
      for (int ot = 0; ot < 8; ++ot) {
        int col = ot * 16 + row16;
        float bi = bp[col];
        #pragma unroll
        for (int r = 0; r < 4; ++r) {
          float v = (acc3[ot][r] + bi) * osc;
          qkvout[(size_t)(m0 + r) * 384 + c3 * 128 + col] = f2bf(v);
        }
      }
    }
  }
}

// ---------------- flash attention (round-12, unchanged) ----------------
// grid = 512: blockIdx.x = (b<<2)|(h<<1)|qhalf. block = 512 (8 waves x 32 queries).
// LDS 36864 B -> 4 blocks/CU. Next stage's K/V reg-prefetched after the barrier.
// No-max softmax (Q pre-scaled; tiny scores). li per-lane, reduced in epilogue.
__global__ __launch_bounds__(512) void k_attn(const short* __restrict__ qkv,
                                              short* __restrict__ O) {
  __shared__ short Kl[64 * 72];     // 64 keys x 64 d, stride 72
  __shared__ short Vtl[64 * 72];    // 64 d x 64 keys, stride 72
  __shared__ short Pl[8][16 * 72];  // per-wave P stash (16 q x 64 k)

  int tid = threadIdx.x, lane = tid & 63, wave = tid >> 6;
  int row16 = lane & 15, quad = lane >> 4;
  int b = blockIdx.x >> 2, h = (blockIdx.x >> 1) & 1, qhalf = blockIdx.x & 1;
  const short* base  = qkv + (size_t)b * S_ * 384;
  const short* kbase = base + 128 + h * 64;
  const short* vbase = base + 256 + h * 64;
  int q0 = qhalf * 256 + wave * 32;

  bf8s qa[2][2];
  #pragma unroll
  for (int qf = 0; qf < 2; ++qf) {
    const short* qrow = base + h * 64 +
        (size_t)(q0 + qf * 16 + row16) * 384 + quad * 8;
    qa[qf][0] = *(const bf8s*)(qrow);
    qa[qf][1] = *(const bf8s*)(qrow + 32);
  }

  int krow = tid >> 3, dgk = tid & 7;
  int vkey = tid & 63, dgv = tid >> 6;
  const short* kptr = kbase + (size_t)krow * 384 + dgk * 8;
  const short* vptr = vbase + (size_t)vkey * 384 + dgv * 8;
  bf8s kst = *(const bf8s*)(kptr);
  bf8s vst = *(const bf8s*)(vptr);

  float li[2][4] = {};
  f32x4 oacc[2][4] = {};
  short* myP = &Pl[wave][0];

  for (int kt0 = 0; kt0 < S_; kt0 += 64) {
    if (kt0) __syncthreads();
    *(bf8s*)(&Kl[krow * 72 + dgk * 8]) = kst;
    #pragma unroll
    for (int j = 0; j < 8; ++j) Vtl[(dgv * 8 + j) * 72 + vkey] = vst[j];
    __syncthreads();
    if (kt0 + 64 < S_) {
      kst = *(const bf8s*)(kptr + (size_t)(kt0 + 64) * 384);
      vst = *(const bf8s*)(vptr + (size_t)(kt0 + 64) * 384);
    }

    f32x4 sc[2][4] = {};
    #pragma unroll
    for (int ks = 0; ks < 4; ++ks) {
      const short* kp = &Kl[(ks * 16 + row16) * 72 + quad * 8];
      bf8s k0 = *(const bf8s*)(kp);
      bf8s k1 = *(const bf8s*)(kp + 32);
      sc[0][ks] = MFMA16(qa[0][0], k0, sc[0][ks]);
      sc[0][ks] = MFMA16(qa[0][1], k1, sc[0][ks]);
      sc[1][ks] = MFMA16(qa[1][0], k0, sc[1][ks]);
      sc[1][ks] = MFMA16(qa[1][1], k1, sc[1][ks]);
    }

    #pragma unroll
    for (int qf = 0; qf < 2; ++qf) {
      #pragma unroll
      for (int ks = 0; ks < 4; ++ks)
        #pragma unroll
        for (int r = 0; r < 4; ++r) {
          float pv = __expf(sc[qf][ks][r]);
          li[qf][r] += pv;
          myP[(quad * 4 + r) * 72 + ks * 16 + row16] = f2bf(pv);
        }
      bf8s pa0 = *(const bf8s*)(&myP[row16 * 72 + quad * 8]);
      bf8s pa1 = *(const bf8s*)(&myP[row16 * 72 + 32 + quad * 8]);
      #pragma unroll
      for (int dt = 0; dt < 4; ++dt) {
        const short* vp = &Vtl[(dt * 16 + row16) * 72 + quad * 8];
        bf8s v0 = *(const bf8s*)(vp);
        bf8s v1 = *(const bf8s*)(vp + 32);
        oacc[qf][dt] = MFMA16(pa0, v0, oacc[qf][dt]);
        oacc[qf][dt] = MFMA16(pa1, v1, oacc[qf][dt]);
      }
    }
  }

  #pragma unroll
  for (int qf = 0; qf < 2; ++qf) {
    float inv[4];
    #pragma unroll
    for (int r = 0; r < 4; ++r) {
      float t = li[qf][r];
      #pragma unroll
      for (int m = 1; m <= 8; m <<= 1) t += __shfl_xor(t, m);
      inv[r] = 1.f / t;
    }
    size_t trow = (size_t)(b * S_ + q0 + qf * 16 + quad * 4);
    #pragma unroll
    for (int dt = 0; dt < 4; ++dt)
      #pragma unroll
      for (int r = 0; r < 4; ++r)
        O[(trow + r) * HID_ + h * 64 + dt * 16 + row16] =
            f2bf(oacc[qf][dt][r] * inv[r]);
  }
}

// ---------------- classifier ----------------
__global__ __launch_bounds__(256) void k_clf(const short* __restrict__ xb,
    const short* __restrict__ Wc, const float* __restrict__ cbias, float* out) {
  int i = threadIdx.x;  // 256 = 128 batches x 2 classes
  int b = i >> 1, c = i & 1;
  float s = 0.f;
  for (int k = 0; k < HID_; ++k)
    s += bf2f(xb[(size_t)b * S_ * HID_ + k]) * bf2f(Wc[c * HID_ + k]);
  out[b * 2 + c] = s + cbias[c];
}

// ---------------- launcher ----------------
extern "C" void kernel_launch(void* const* d_in, const int* in_sizes, int n_in,
                              void* d_out, int out_size, void* d_ws, size_t ws_size,
                              hipStream_t stream) {
  const int*   ids     = (const int*)d_in[0];
  const float* tok_emb = (const float*)d_in[1];
  const float* pos_emb = (const float*)d_in[2];
  const float* ln_g    = (const float*)d_in[3];
  const float* ln_bb   = (const float*)d_in[4];
  const float* qw      = (const float*)d_in[5];
  const float* qbias   = (const float*)d_in[6];
  const float* kw      = (const float*)d_in[7];
  const float* kbias   = (const float*)d_in[8];
  const float* vw      = (const float*)d_in[9];
  const float* vbias   = (const float*)d_in[10];
  const float* aow     = (const float*)d_in[11];
  const float* aobias  = (const float*)d_in[12];
  const float* iw      = (const float*)d_in[13];
  const float* ibias   = (const float*)d_in[14];
  const float* fow     = (const float*)d_in[15];
  const float* fbias   = (const float*)d_in[16];
  const float* ln1g    = (const float*)d_in[17];
  const float* ln1b    = (const float*)d_in[18];
  const float* ln2g    = (const float*)d_in[19];
  const float* ln2b    = (const float*)d_in[20];
  const float* clfw    = (const float*)d_in[21];
  const float* clfb    = (const float*)d_in[22];

  char* ws = (char*)d_ws;
  short* WQ  = (short*)ws;                                   // 787 KB quantized weights
  short* xb  = (short*)(ws + 1048576);                       // bf16 trunk (16.8 MB)
  short* qkv = (short*)(ws + 1048576 + 16777216);            // [tok][384] (50.3 MB)
  short* cb_ = qkv + (size_t)M_ * 384;                       // ctx [tok][128] (16.8 MB)

  k_qe<<<13 + M_ / 16, 1024, 0, stream>>>(qw, kw, vw, aow, iw, fow, clfw, WQ,
                                          ids, tok_emb, pos_emb, ln_g, ln_bb, xb);

  const short* Wqkv0 = WQ;
  const short* Wqkv1 = WQ + 49152;
  const short* Wa0   = WQ + 98304;
  const short* Wa1   = WQ + 98304 + 16384;
  const short* Wi0   = WQ + 131072;
  const short* Wi1   = WQ + 131072 + 65536;
  const short* Wf0   = WQ + 262144;
  const short* Wf1   = WQ + 262144 + 65536;

  // layer 0 (k_aoff tail computes layer-1 QKV)
  k_qkv<<<dim3(M_ / 64, 3), 256, 0, stream>>>(
      xb, Wqkv0, qbias, kbias, vbias, qkv);
  k_attn<<<512, 512, 0, stream>>>(qkv, cb_);
  k_aoff<1><<<M_ / 128, 512, 0, stream>>>(
      cb_, Wa0, aobias, ln1g, ln1b, Wi0, Wf0, ibias, fbias, ln2g, ln2b, xb,
      Wqkv1, qbias + HID_, kbias + HID_, vbias + HID_, qkv);
  // layer 1
  k_attn<<<512, 512, 0, stream>>>(qkv, cb_);
  k_aoff<0><<<M_ / 128, 512, 0, stream>>>(
      cb_, Wa1, aobias + HID_, ln1g + HID_, ln1b + HID_, Wi1, Wf1,
      ibias + 512, fbias + HID_, ln2g + HID_, ln2b + HID_, xb,
      nullptr, nullptr, nullptr, nullptr, nullptr);

  k_clf<<<1, 256, 0, stream>>>(xb, WQ + 393216, clfb, (float*)d_out);
}

// Round 14
// 322.378 us; speedup vs baseline: 1.5699x; 1.0196x over previous
//
#include <hip/hip_runtime.h>

// ---------------- types / helpers ----------------
typedef short bf8s __attribute__((ext_vector_type(8)));   // 8 bf16 (4 VGPRs)
typedef float f32x4 __attribute__((ext_vector_type(4)));

#define MFMA16(a, b, c) __builtin_amdgcn_mfma_f32_16x16x32_bf16(a, b, c, 0, 0, 0)

constexpr int S_ = 512, HID_ = 128, B_ = 128, M_ = B_ * S_;

__device__ inline short f2bf(float f) {  // fp32 -> bf16 (RNE)
  unsigned u = __float_as_uint(f);
  u = (u + 0x7fffu + ((u >> 16) & 1u)) >> 16;
  return (short)u;
}
__device__ inline float bf2f(short s) {
  return __uint_as_float(((unsigned)(unsigned short)s) << 16);
}

__device__ inline float block_red1024(float v, float* red) {
  #pragma unroll
  for (int m = 32; m >= 1; m >>= 1) v += __shfl_xor(v, m);
  __syncthreads();
  if ((threadIdx.x & 63) == 0) red[threadIdx.x >> 6] = v;
  __syncthreads();
  float t = 0.f;
  #pragma unroll
  for (int i = 0; i < 16; ++i) t += red[i];
  return t;
}

// matrix table. doff layout (shorts):
//  per-layer QKV contiguous: l*49152 + {q:0,k:16384,v:32768}
//  ao: 98304 + l*16384 ; iw: 131072 + l*65536 ; fow: 262144 + l*65536 ; clf: 393216
__device__ inline void mat_info(int mat, const float* qw, const float* kw,
                                const float* vw, const float* aow, const float* iw,
                                const float* fw, const float* cw,
                                const float** src, int* n, int* doff) {
  if (mat < 6) {
    int l = mat / 3, which = mat % 3;
    const float* t[3] = {qw, kw, vw};
    *src = t[which] + l * 16384; *n = 16384; *doff = l * 49152 + which * 16384;
  } else if (mat < 8) {
    int l = mat - 6;
    *src = aow + l * 16384; *n = 16384; *doff = 98304 + l * 16384;
  } else if (mat < 10) {
    *src = iw + (mat - 8) * 65536; *n = 65536; *doff = 131072 + (mat - 8) * 65536;
  } else if (mat < 12) {
    *src = fw + (mat - 10) * 65536; *n = 65536; *doff = 262144 + (mat - 10) * 65536;
  } else {
    *src = cw; *n = 256; *doff = 393216;
  }
}

// ---------------- fused quant (blocks 0..12) + embed (blocks 13..) ----------------
__global__ __launch_bounds__(1024) void k_qe(const float* qw, const float* kw,
    const float* vw, const float* aow, const float* iw, const float* fw,
    const float* cw, short* WQ,
    const int* __restrict__ ids, const float* __restrict__ tok,
    const float* __restrict__ pos, const float* __restrict__ g,
    const float* __restrict__ bb, short* xb) {
  __shared__ float red[16];
  int tid = threadIdx.x;
  if (blockIdx.x < 13) {  // ---- ternary quantization ----
    const float* src; int n, doff;
    mat_info(blockIdx.x, qw, kw, vw, aow, iw, fw, cw, &src, &n, &doff);
    float s = 0.f;
    for (int i = tid; i < n; i += 1024) s += fabsf(src[i]);
    s = block_red1024(s, red);
    float delta = 0.7f * s / (float)n;
    float s2 = 0.f, c2 = 0.f;
    for (int i = tid; i < n; i += 1024) {
      float a = fabsf(src[i]);
      if (a > delta) { s2 += a; c2 += 1.f; }
    }
    s2 = block_red1024(s2, red);
    c2 = block_red1024(c2, red);
    float alpha = s2 / fmaxf(c2, 1.f);
    for (int i = tid; i < n; i += 1024) {
      float w = src[i];
      WQ[doff + i] = (fabsf(w) > delta) ? f2bf(w > 0.f ? alpha : -alpha) : (short)0;
    }
  } else {  // ---- embedding + LN ----
    int wave = tid >> 6, lane = tid & 63;
    int t = (blockIdx.x - 13) * 16 + wave;
    int s = t & (S_ - 1);
    int id = ids[t];
    float e0 = tok[(size_t)id * HID_ + lane] + pos[(size_t)s * HID_ + lane];
    float e1 = tok[(size_t)id * HID_ + 64 + lane] + pos[(size_t)s * HID_ + 64 + lane];
    float sum = e0 + e1, ssq = e0 * e0 + e1 * e1;
    #pragma unroll
    for (int m = 32; m >= 1; m >>= 1) {
      sum += __shfl_xor(sum, m);
      ssq += __shfl_xor(ssq, m);
    }
    float mean = sum / 128.f;
    float var = ssq / 128.f - mean * mean;
    float rs = rsqrtf(var + 1e-5f);
    size_t o = (size_t)t * HID_;
    xb[o + lane]      = f2bf((e0 - mean) * rs * g[lane] + bb[lane]);
    xb[o + 64 + lane] = f2bf((e1 - mean) * rs * g[64 + lane] + bb[64 + lane]);
  }
}

// ---------------- QKV linear (layer 0 only): 64-tok blocks, stride-144 LDS ----------------
__global__ __launch_bounds__(256) void k_qkv(
    const short* __restrict__ A, const short* __restrict__ W,
    const float* __restrict__ b0, const float* __restrict__ b1,
    const float* __restrict__ b2, short* outb) {
  __shared__ short Wl[128 * 144];  // 144 shorts = 72 words (8 mod 32): 4-way not 8-way
  int tid = threadIdx.x, lane = tid & 63, wave = tid >> 6;
  int row16 = lane & 15, quad = lane >> 4;
  int tok0 = blockIdx.x * 64 + wave * 16;
  int nbase = blockIdx.y * 128;

  const short* arow = A + (size_t)(tok0 + row16) * 128 + quad * 8;
  bf8s av[4];
  #pragma unroll
  for (int ki = 0; ki < 4; ++ki) av[ki] = *(const bf8s*)(arow + ki * 32);

  {
    int r = tid >> 1, half = tid & 1;
    const short* src = W + (size_t)(nbase + r) * 128 + half * 64;
    short* dst = &Wl[r * 144 + half * 64];
    #pragma unroll
    for (int j = 0; j < 8; ++j)
      *(bf8s*)(dst + j * 8) = *(const bf8s*)(src + j * 8);
  }
  __syncthreads();

  f32x4 acc[8] = {};
  #pragma unroll
  for (int ki = 0; ki < 4; ++ki)
    #pragma unroll
    for (int ot = 0; ot < 8; ++ot) {
      bf8s b = *(const bf8s*)(&Wl[(ot * 16 + row16) * 144 + ki * 32 + quad * 8]);
      acc[ot] = MFMA16(av[ki], b, acc[ot]);
    }

  const float* bp = (blockIdx.y == 0) ? b0 : ((blockIdx.y == 1) ? b1 : b2);
  float osc = (blockIdx.y == 0) ? 0.125f : 1.0f;  // fold 1/sqrt(64) into Q
  int m0 = tok0 + quad * 4;
  #pragma unroll
  for (int ot = 0; ot < 8; ++ot) {
    int col = ot * 16 + row16;
    float bi = bp[col];
    #pragma unroll
    for (int r = 0; r < 4; ++r) {
      float v = (acc[ot][r] + bi) * osc;
      outb[(size_t)(m0 + r) * 384 + nbase + col] = f2bf(v);
    }
  }
}

// ---------------- fused AO+LN1+FF1+FF2+LN2 [+ next-layer QKV] ----------------
// 512 threads / 128 tokens (grid 512 = exactly 2 blocks/CU).
// Round-13 diagnosis: allocator chose 68 VGPR (8-waves/EU heuristic; LDS caps
// us at 4 waves/EU anyway) -> ~31 MB spill, dur 56->72. Fixes: (1) drop the
// wiR/wfR reg-prefetch (round-12: measured neutral; 16 regs back) -> direct
// global->LDS staging in the barrier window; (2) __launch_bounds__(512, 2)
// (min 2 waves/EU -> 256 VGPR cap; round-4/5 512-thr kernels allocated 128
// under this bound). Live state now ~74 regs.
// LDS: phase A Wa 128x144=18432sh | FF: SWi 64x144=9216 + SWf 128x80=10240 +
// stash 8x16x80=10240 = 29696sh (59392 B) -> 2 blocks/CU.
template <int DOQKV>
__global__ __launch_bounds__(512, 2) void k_aoff(
    const short* __restrict__ cb, const short* __restrict__ Wa,
    const float* __restrict__ aob, const float* __restrict__ ln1g,
    const float* __restrict__ ln1b, const short* __restrict__ Wi,
    const short* __restrict__ Wf, const float* __restrict__ ib,
    const float* __restrict__ fb, const float* __restrict__ ln2g,
    const float* __restrict__ ln2b, short* xb,
    const short* __restrict__ Wqkv2, const float* __restrict__ qb2,
    const float* __restrict__ kb2, const float* __restrict__ vb2,
    short* qkvout) {
  __shared__ short SM[29696];
  int tid = threadIdx.x, lane = tid & 63, wave = tid >> 6;
  int row16 = lane & 15, quad = lane >> 4;
  int tok0 = blockIdx.x * 128 + wave * 16;
  int m0 = tok0 + quad * 4;

  // ---- phase A: AO linear ----
  const short* arow = cb + (size_t)(tok0 + row16) * 128 + quad * 8;
  bf8s av[4];
  #pragma unroll
  for (int ki = 0; ki < 4; ++ki) av[ki] = *(const bf8s*)(arow + ki * 32);

  {  // stage Wa 128x128 (stride 144): 4 threads/row, 32 shorts each
    int r = tid >> 2, q4 = tid & 3;
    const short* src = Wa + (size_t)r * 128 + q4 * 32;
    short* dst = &SM[r * 144 + q4 * 32];
    #pragma unroll
    for (int j = 0; j < 4; ++j)
      *(bf8s*)(dst + j * 8) = *(const bf8s*)(src + j * 8);
  }
  __syncthreads();

  f32x4 acc[8] = {};
  #pragma unroll
  for (int ki = 0; ki < 4; ++ki)
    #pragma unroll
    for (int ot = 0; ot < 8; ++ot) {
      bf8s b = *(const bf8s*)(&SM[(ot * 16 + row16) * 144 + ki * 32 + quad * 8]);
      acc[ot] = MFMA16(av[ki], b, acc[ot]);
    }

  // AO epilogue: bias + residual + LN1 -> x'
  {
    float sum[4] = {}, ssq[4] = {};
    #pragma unroll
    for (int ot = 0; ot < 8; ++ot) {
      int col = ot * 16 + row16;
      float bi = aob[col];
      #pragma unroll
      for (int r = 0; r < 4; ++r) {
        float v = acc[ot][r] + bi + bf2f(xb[(size_t)(m0 + r) * HID_ + col]);
        acc[ot][r] = v;
        sum[r] += v; ssq[r] += v * v;
      }
    }
    #pragma unroll
    for (int m = 1; m <= 8; m <<= 1)
      #pragma unroll
      for (int r = 0; r < 4; ++r) {
        sum[r] += __shfl_xor(sum[r], m);
        ssq[r] += __shfl_xor(ssq[r], m);
      }
    float mean[4], rstd[4];
    #pragma unroll
    for (int r = 0; r < 4; ++r) {
      mean[r] = sum[r] / 128.f;
      float var = ssq[r] / 128.f - mean[r] * mean[r];
      rstd[r] = rsqrtf(var + 1e-5f);
    }
    #pragma unroll
    for (int ot = 0; ot < 8; ++ot) {
      int col = ot * 16 + row16;
      float gg = ln1g[col], bb2 = ln1b[col];
      #pragma unroll
      for (int r = 0; r < 4; ++r)
        acc[ot][r] = (acc[ot][r] - mean[r]) * rstd[r] * gg + bb2;  // x'
    }
  }

  // spill x' (bf16) to xb's own rows (dead until FF epilogue) -> frees acc regs
  #pragma unroll
  for (int ot = 0; ot < 8; ++ot) {
    int col = ot * 16 + row16;
    #pragma unroll
    for (int r = 0; r < 4; ++r)
      xb[(size_t)(m0 + r) * HID_ + col] = f2bf(acc[ot][r]);
  }

  // transpose x' -> A-frags through the (dead) Wa region; wave-private slice
  __syncthreads();
  {
    short* myX = &SM[wave * 2304];  // 16 rows x stride 144
    #pragma unroll
    for (int ot = 0; ot < 8; ++ot)
      #pragma unroll
      for (int r = 0; r < 4; ++r)
        myX[(quad * 4 + r) * 144 + ot * 16 + row16] = f2bf(acc[ot][r]);
    #pragma unroll
    for (int ki = 0; ki < 4; ++ki)
      av[ki] = *(const bf8s*)(myX + row16 * 144 + ki * 32 + quad * 8);
  }

  // ---- phase B: FF over 8 inter-chunks (direct global->LDS staging) ----
  int rwi = tid >> 3, q8 = tid & 7;   // Wi: 64 rows x 8 groups of 16 shorts
  int rwf = tid >> 2, qf4 = tid & 3;  // Wf: 128 rows x 4 groups of 16 shorts
  short* SWi = SM;                         // 64 x 144
  short* SWf = SM + 9216;                  // 128 x 80
  short* mySt = SM + 19456 + wave * 1280;  // 16 x 80 per wave
  f32x4 acc2[8] = {};
  for (int c = 0; c < 8; ++c) {
    __syncthreads();  // c==0: myX reads done; else: previous SWi/SWf reads done
    {  // stage Wi+Wf chunk: all 4 global loads issued before any LDS write
      const short* ws1 = Wi + (size_t)(c * 64 + rwi) * HID_ + q8 * 16;
      const short* ws2 = Wf + (size_t)rwf * 512 + c * 64 + qf4 * 16;
      bf8s a0 = *(const bf8s*)(ws1);
      bf8s a1 = *(const bf8s*)(ws1 + 8);
      bf8s b0 = *(const bf8s*)(ws2);
      bf8s b1 = *(const bf8s*)(ws2 + 8);
      short* dwi = SWi + rwi * 144 + q8 * 16;
      short* dwf = SWf + rwf * 80 + qf4 * 16;
      *(bf8s*)(dwi) = a0; *(bf8s*)(dwi + 8) = a1;
      *(bf8s*)(dwf) = b0; *(bf8s*)(dwf + 8) = b1;
    }
    __syncthreads();

    f32x4 hacc[4] = {};
    #pragma unroll
    for (int ki = 0; ki < 4; ++ki)
      #pragma unroll
      for (int ot = 0; ot < 4; ++ot) {
        bf8s b = *(const bf8s*)(SWi + (ot * 16 + row16) * 144 + ki * 32 + quad * 8);
        hacc[ot] = MFMA16(av[ki], b, hacc[ot]);
      }
    #pragma unroll
    for (int ot = 0; ot < 4; ++ot) {
      float bi = ib[c * 64 + ot * 16 + row16];
      #pragma unroll
      for (int r = 0; r < 4; ++r)
        mySt[(quad * 4 + r) * 80 + ot * 16 + row16] =
            f2bf(fmaxf(hacc[ot][r] + bi, 0.f));
    }
    bf8s ha0 = *(const bf8s*)(mySt + row16 * 80 + quad * 8);
    bf8s ha1 = *(const bf8s*)(mySt + row16 * 80 + 32 + quad * 8);
    #pragma unroll
    for (int ot = 0; ot < 8; ++ot) {
      bf8s bA = *(const bf8s*)(SWf + (ot * 16 + row16) * 80 + quad * 8);
      bf8s bB = *(const bf8s*)(SWf + (ot * 16 + row16) * 80 + 32 + quad * 8);
      acc2[ot] = MFMA16(ha0, bA, acc2[ot]);
      acc2[ot] = MFMA16(ha1, bB, acc2[ot]);
    }
  }

  // FF epilogue: + fb + x'(from xb) + LN2 -> x'' in acc2; write xb
  {
    float sum[4] = {}, ssq[4] = {};
    #pragma unroll
    for (int ot = 0; ot < 8; ++ot) {
      int col = ot * 16 + row16;
      float bi = fb[col];
      #pragma unroll
      for (int r = 0; r < 4; ++r) {
        float v = acc2[ot][r] + bi + bf2f(xb[(size_t)(m0 + r) * HID_ + col]);
        acc2[ot][r] = v;
        sum[r] += v; ssq[r] += v * v;
      }
    }
    #pragma unroll
    for (int m = 1; m <= 8; m <<= 1)
      #pragma unroll
      for (int r = 0; r < 4; ++r) {
        sum[r] += __shfl_xor(sum[r], m);
        ssq[r] += __shfl_xor(ssq[r], m);
      }
    float mean[4], rstd[4];
    #pragma unroll
    for (int r = 0; r < 4; ++r) {
      mean[r] = sum[r] / 128.f;
      float var = ssq[r] / 128.f - mean[r] * mean[r];
      rstd[r] = rsqrtf(var + 1e-5f);
    }
    #pragma unroll
    for (int ot = 0; ot < 8; ++ot) {
      int col = ot * 16 + row16;
      float gg = ln2g[col], bb2 = ln2b[col];
      #pragma unroll
      for (int r = 0; r < 4; ++r) {
        float v = (acc2[ot][r] - mean[r]) * rstd[r] * gg + bb2;
        acc2[ot][r] = v;
        xb[(size_t)(m0 + r) * HID_ + col] = f2bf(v);
      }
    }
  }

  if (DOQKV) {
    // ---- tail: next-layer QKV for our own 128 tokens ----
    __syncthreads();  // all FF LDS reads done
    bf8s av2[4];
    {
      short* myX = &SM[wave * 2304];  // 16 rows x stride 144
      #pragma unroll
      for (int ot = 0; ot < 8; ++ot)
        #pragma unroll
        for (int r = 0; r < 4; ++r)
          myX[(quad * 4 + r) * 144 + ot * 16 + row16] = f2bf(acc2[ot][r]);
      #pragma unroll
      for (int ki = 0; ki < 4; ++ki)
        av2[ki] = *(const bf8s*)(myX + row16 * 144 + ki * 32 + quad * 8);
    }
    for (int c3 = 0; c3 < 3; ++c3) {
      __syncthreads();  // protects myX (c3==0) / previous chunk reads
      {  // stage Wqkv chunk 128x128 (stride 144): 4 threads/row
        int r = tid >> 2, q4 = tid & 3;
        const short* src = Wqkv2 + (size_t)(c3 * 128 + r) * 128 + q4 * 32;
        short* dst = &SM[r * 144 + q4 * 32];
        #pragma unroll
        for (int j = 0; j < 4; ++j)
          *(bf8s*)(dst + j * 8) = *(const bf8s*)(src + j * 8);
      }
      __syncthreads();
      f32x4 acc3[8] = {};
      #pragma unroll
      for (int ki = 0; ki < 4; ++ki)
        #pragma unroll
        for (int ot = 0; ot < 8; ++ot) {
          bf8s b = *(const bf8s*)(&SM[(ot * 16 + row16) * 144 + ki * 32 + quad * 8]);
          acc3[ot] = MFMA16(av2[ki], b, acc3[ot]);
        }
      const float* bp = (c3 == 0) ? qb2 : ((c3 == 1) ? kb2 : vb2);
      float osc = (c3 == 0) ? 0.125f : 1.0f;
      #pragma unroll
      for (int ot = 0; ot < 8; ++ot) {
        int col = ot * 16 + row16;
        float bi = bp[col];
        #pragma unroll
        for (int r = 0; r < 4; ++r) {
          float v = (acc3[ot][r] + bi) * osc;
          qkvout[(size_t)(m0 + r) * 384 + c3 * 128 + col] = f2bf(v);
        }
      }
    }
  }
}

// ---------------- flash attention (round-12, unchanged) ----------------
// grid = 512: blockIdx.x = (b<<2)|(h<<1)|qhalf. block = 512 (8 waves x 32 queries).
// LDS 36864 B -> 4 blocks/CU. Next stage's K/V reg-prefetched after the barrier.
// No-max softmax (Q pre-scaled; tiny scores). li per-lane, reduced in epilogue.
__global__ __launch_bounds__(512) void k_attn(const short* __restrict__ qkv,
                                              short* __restrict__ O) {
  __shared__ short Kl[64 * 72];     // 64 keys x 64 d, stride 72
  __shared__ short Vtl[64 * 72];    // 64 d x 64 keys, stride 72
  __shared__ short Pl[8][16 * 72];  // per-wave P stash (16 q x 64 k)

  int tid = threadIdx.x, lane = tid & 63, wave = tid >> 6;
  int row16 = lane & 15, quad = lane >> 4;
  int b = blockIdx.x >> 2, h = (blockIdx.x >> 1) & 1, qhalf = blockIdx.x & 1;
  const short* base  = qkv + (size_t)b * S_ * 384;
  const short* kbase = base + 128 + h * 64;
  const short* vbase = base + 256 + h * 64;
  int q0 = qhalf * 256 + wave * 32;

  bf8s qa[2][2];
  #pragma unroll
  for (int qf = 0; qf < 2; ++qf) {
    const short* qrow = base + h * 64 +
        (size_t)(q0 + qf * 16 + row16) * 384 + quad * 8;
    qa[qf][0] = *(const bf8s*)(qrow);
    qa[qf][1] = *(const bf8s*)(qrow + 32);
  }

  int krow = tid >> 3, dgk = tid & 7;
  int vkey = tid & 63, dgv = tid >> 6;
  const short* kptr = kbase + (size_t)krow * 384 + dgk * 8;
  const short* vptr = vbase + (size_t)vkey * 384 + dgv * 8;
  bf8s kst = *(const bf8s*)(kptr);
  bf8s vst = *(const bf8s*)(vptr);

  float li[2][4] = {};
  f32x4 oacc[2][4] = {};
  short* myP = &Pl[wave][0];

  for (int kt0 = 0; kt0 < S_; kt0 += 64) {
    if (kt0) __syncthreads();
    *(bf8s*)(&Kl[krow * 72 + dgk * 8]) = kst;
    #pragma unroll
    for (int j = 0; j < 8; ++j) Vtl[(dgv * 8 + j) * 72 + vkey] = vst[j];
    __syncthreads();
    if (kt0 + 64 < S_) {
      kst = *(const bf8s*)(kptr + (size_t)(kt0 + 64) * 384);
      vst = *(const bf8s*)(vptr + (size_t)(kt0 + 64) * 384);
    }

    f32x4 sc[2][4] = {};
    #pragma unroll
    for (int ks = 0; ks < 4; ++ks) {
      const short* kp = &Kl[(ks * 16 + row16) * 72 + quad * 8];
      bf8s k0 = *(const bf8s*)(kp);
      bf8s k1 = *(const bf8s*)(kp + 32);
      sc[0][ks] = MFMA16(qa[0][0], k0, sc[0][ks]);
      sc[0][ks] = MFMA16(qa[0][1], k1, sc[0][ks]);
      sc[1][ks] = MFMA16(qa[1][0], k0, sc[1][ks]);
      sc[1][ks] = MFMA16(qa[1][1], k1, sc[1][ks]);
    }

    #pragma unroll
    for (int qf = 0; qf < 2; ++qf) {
      #pragma unroll
      for (int ks = 0; ks < 4; ++ks)
        #pragma unroll
        for (int r = 0; r < 4; ++r) {
          float pv = __expf(sc[qf][ks][r]);
          li[qf][r] += pv;
          myP[(quad * 4 + r) * 72 + ks * 16 + row16] = f2bf(pv);
        }
      bf8s pa0 = *(const bf8s*)(&myP[row16 * 72 + quad * 8]);
      bf8s pa1 = *(const bf8s*)(&myP[row16 * 72 + 32 + quad * 8]);
      #pragma unroll
      for (int dt = 0; dt < 4; ++dt) {
        const short* vp = &Vtl[(dt * 16 + row16) * 72 + quad * 8];
        bf8s v0 = *(const bf8s*)(vp);
        bf8s v1 = *(const bf8s*)(vp + 32);
        oacc[qf][dt] = MFMA16(pa0, v0, oacc[qf][dt]);
        oacc[qf][dt] = MFMA16(pa1, v1, oacc[qf][dt]);
      }
    }
  }

  #pragma unroll
  for (int qf = 0; qf < 2; ++qf) {
    float inv[4];
    #pragma unroll
    for (int r = 0; r < 4; ++r) {
      float t = li[qf][r];
      #pragma unroll
      for (int m = 1; m <= 8; m <<= 1) t += __shfl_xor(t, m);
      inv[r] = 1.f / t;
    }
    size_t trow = (size_t)(b * S_ + q0 + qf * 16 + quad * 4);
    #pragma unroll
    for (int dt = 0; dt < 4; ++dt)
      #pragma unroll
      for (int r = 0; r < 4; ++r)
        O[(trow + r) * HID_ + h * 64 + dt * 16 + row16] =
            f2bf(oacc[qf][dt][r] * inv[r]);
  }
}

// ---------------- classifier ----------------
__global__ __launch_bounds__(256) void k_clf(const short* __restrict__ xb,
    const short* __restrict__ Wc, const float* __restrict__ cbias, float* out) {
  int i = threadIdx.x;  // 256 = 128 batches x 2 classes
  int b = i >> 1, c = i & 1;
  float s = 0.f;
  for (int k = 0; k < HID_; ++k)
    s += bf2f(xb[(size_t)b * S_ * HID_ + k]) * bf2f(Wc[c * HID_ + k]);
  out[b * 2 + c] = s + cbias[c];
}

// ---------------- launcher ----------------
extern "C" void kernel_launch(void* const* d_in, const int* in_sizes, int n_in,
                              void* d_out, int out_size, void* d_ws, size_t ws_size,
                              hipStream_t stream) {
  const int*   ids     = (const int*)d_in[0];
  const float* tok_emb = (const float*)d_in[1];
  const float* pos_emb = (const float*)d_in[2];
  const float* ln_g    = (const float*)d_in[3];
  const float* ln_bb   = (const float*)d_in[4];
  const float* qw      = (const float*)d_in[5];
  const float* qbias   = (const float*)d_in[6];
  const float* kw      = (const float*)d_in[7];
  const float* kbias   = (const float*)d_in[8];
  const float* vw      = (const float*)d_in[9];
  const float* vbias   = (const float*)d_in[10];
  const float* aow     = (const float*)d_in[11];
  const float* aobias  = (const float*)d_in[12];
  const float* iw      = (const float*)d_in[13];
  const float* ibias   = (const float*)d_in[14];
  const float* fow     = (const float*)d_in[15];
  const float* fbias   = (const float*)d_in[16];
  const float* ln1g    = (const float*)d_in[17];
  const float* ln1b    = (const float*)d_in[18];
  const float* ln2g    = (const float*)d_in[19];
  const float* ln2b    = (const float*)d_in[20];
  const float* clfw    = (const float*)d_in[21];
  const float* clfb    = (const float*)d_in[22];

  char* ws = (char*)d_ws;
  short* WQ  = (short*)ws;                                   // 787 KB quantized weights
  short* xb  = (short*)(ws + 1048576);                       // bf16 trunk (16.8 MB)
  short* qkv = (short*)(ws + 1048576 + 16777216);            // [tok][384] (50.3 MB)
  short* cb_ = qkv + (size_t)M_ * 384;                       // ctx [tok][128] (16.8 MB)

  k_qe<<<13 + M_ / 16, 1024, 0, stream>>>(qw, kw, vw, aow, iw, fow, clfw, WQ,
                                          ids, tok_emb, pos_emb, ln_g, ln_bb, xb);

  const short* Wqkv0 = WQ;
  const short* Wqkv1 = WQ + 49152;
  const short* Wa0   = WQ + 98304;
  const short* Wa1   = WQ + 98304 + 16384;
  const short* Wi0   = WQ + 131072;
  const short* Wi1   = WQ + 131072 + 65536;
  const short* Wf0   = WQ + 262144;
  const short* Wf1   = WQ + 262144 + 65536;

  // layer 0 (k_aoff tail computes layer-1 QKV)
  k_qkv<<<dim3(M_ / 64, 3), 256, 0, stream>>>(
      xb, Wqkv0, qbias, kbias, vbias, qkv);
  k_attn<<<512, 512, 0, stream>>>(qkv, cb_);
  k_aoff<1><<<M_ / 128, 512, 0, stream>>>(
      cb_, Wa0, aobias, ln1g, ln1b, Wi0, Wf0, ibias, fbias, ln2g, ln2b, xb,
      Wqkv1, qbias + HID_, kbias + HID_, vbias + HID_, qkv);
  // layer 1
  k_attn<<<512, 512, 0, stream>>>(qkv, cb_);
  k_aoff<0><<<M_ / 128, 512, 0, stream>>>(
      cb_, Wa1, aobias + HID_, ln1g + HID_, ln1b + HID_, Wi1, Wf1,
      ibias + 512, fbias + HID_, ln2g + HID_, ln2b + HID_, xb,
      nullptr, nullptr, nullptr, nullptr, nullptr);

  k_clf<<<1, 256, 0, stream>>>(xb, WQ + 393216, clfb, (float*)d_out);
}

// Round 15
// 319.105 us; speedup vs baseline: 1.5860x; 1.0103x over previous
//
#include <hip/hip_runtime.h>

// ---------------- types / helpers ----------------
typedef short bf8s __attribute__((ext_vector_type(8)));   // 8 bf16 (4 VGPRs)
typedef float f32x4 __attribute__((ext_vector_type(4)));

#define MFMA16(a, b, c) __builtin_amdgcn_mfma_f32_16x16x32_bf16(a, b, c, 0, 0, 0)

constexpr int S_ = 512, HID_ = 128, B_ = 128, M_ = B_ * S_;

__device__ inline short f2bf(float f) {  // fp32 -> bf16 (RNE)
  unsigned u = __float_as_uint(f);
  u = (u + 0x7fffu + ((u >> 16) & 1u)) >> 16;
  return (short)u;
}
__device__ inline float bf2f(short s) {
  return __uint_as_float(((unsigned)(unsigned short)s) << 16);
}

__device__ inline float block_red1024(float v, float* red) {
  #pragma unroll
  for (int m = 32; m >= 1; m >>= 1) v += __shfl_xor(v, m);
  __syncthreads();
  if ((threadIdx.x & 63) == 0) red[threadIdx.x >> 6] = v;
  __syncthreads();
  float t = 0.f;
  #pragma unroll
  for (int i = 0; i < 16; ++i) t += red[i];
  return t;
}

// matrix table. doff layout (shorts):
//  per-layer QKV contiguous: l*49152 + {q:0,k:16384,v:32768}
//  ao: 98304 + l*16384 ; iw: 131072 + l*65536 ; fow: 262144 + l*65536 ; clf: 393216
__device__ inline void mat_info(int mat, const float* qw, const float* kw,
                                const float* vw, const float* aow, const float* iw,
                                const float* fw, const float* cw,
                                const float** src, int* n, int* doff) {
  if (mat < 6) {
    int l = mat / 3, which = mat % 3;
    const float* t[3] = {qw, kw, vw};
    *src = t[which] + l * 16384; *n = 16384; *doff = l * 49152 + which * 16384;
  } else if (mat < 8) {
    int l = mat - 6;
    *src = aow + l * 16384; *n = 16384; *doff = 98304 + l * 16384;
  } else if (mat < 10) {
    *src = iw + (mat - 8) * 65536; *n = 65536; *doff = 131072 + (mat - 8) * 65536;
  } else if (mat < 12) {
    *src = fw + (mat - 10) * 65536; *n = 65536; *doff = 262144 + (mat - 10) * 65536;
  } else {
    *src = cw; *n = 256; *doff = 393216;
  }
}

// ---------------- fused quant (blocks 0..12) + embed (blocks 13..) ----------------
__global__ __launch_bounds__(1024) void k_qe(const float* qw, const float* kw,
    const float* vw, const float* aow, const float* iw, const float* fw,
    const float* cw, short* WQ,
    const int* __restrict__ ids, const float* __restrict__ tok,
    const float* __restrict__ pos, const float* __restrict__ g,
    const float* __restrict__ bb, short* xb) {
  __shared__ float red[16];
  int tid = threadIdx.x;
  if (blockIdx.x < 13) {  // ---- ternary quantization ----
    const float* src; int n, doff;
    mat_info(blockIdx.x, qw, kw, vw, aow, iw, fw, cw, &src, &n, &doff);
    float s = 0.f;
    for (int i = tid; i < n; i += 1024) s += fabsf(src[i]);
    s = block_red1024(s, red);
    float delta = 0.7f * s / (float)n;
    float s2 = 0.f, c2 = 0.f;
    for (int i = tid; i < n; i += 1024) {
      float a = fabsf(src[i]);
      if (a > delta) { s2 += a; c2 += 1.f; }
    }
    s2 = block_red1024(s2, red);
    c2 = block_red1024(c2, red);
    float alpha = s2 / fmaxf(c2, 1.f);
    for (int i = tid; i < n; i += 1024) {
      float w = src[i];
      WQ[doff + i] = (fabsf(w) > delta) ? f2bf(w > 0.f ? alpha : -alpha) : (short)0;
    }
  } else {  // ---- embedding + LN ----
    int wave = tid >> 6, lane = tid & 63;
    int t = (blockIdx.x - 13) * 16 + wave;
    int s = t & (S_ - 1);
    int id = ids[t];
    float e0 = tok[(size_t)id * HID_ + lane] + pos[(size_t)s * HID_ + lane];
    float e1 = tok[(size_t)id * HID_ + 64 + lane] + pos[(size_t)s * HID_ + 64 + lane];
    float sum = e0 + e1, ssq = e0 * e0 + e1 * e1;
    #pragma unroll
    for (int m = 32; m >= 1; m >>= 1) {
      sum += __shfl_xor(sum, m);
      ssq += __shfl_xor(ssq, m);
    }
    float mean = sum / 128.f;
    float var = ssq / 128.f - mean * mean;
    float rs = rsqrtf(var + 1e-5f);
    size_t o = (size_t)t * HID_;
    xb[o + lane]      = f2bf((e0 - mean) * rs * g[lane] + bb[lane]);
    xb[o + 64 + lane] = f2bf((e1 - mean) * rs * g[64 + lane] + bb[64 + lane]);
  }
}

// ---------------- QKV linear (layer 0 only): 64-tok blocks, stride-144 LDS ----------------
__global__ __launch_bounds__(256) void k_qkv(
    const short* __restrict__ A, const short* __restrict__ W,
    const float* __restrict__ b0, const float* __restrict__ b1,
    const float* __restrict__ b2, short* outb) {
  __shared__ short Wl[128 * 144];  // 144 shorts = 72 words (8 mod 32): 4-way not 8-way
  int tid = threadIdx.x, lane = tid & 63, wave = tid >> 6;
  int row16 = lane & 15, quad = lane >> 4;
  int tok0 = blockIdx.x * 64 + wave * 16;
  int nbase = blockIdx.y * 128;

  const short* arow = A + (size_t)(tok0 + row16) * 128 + quad * 8;
  bf8s av[4];
  #pragma unroll
  for (int ki = 0; ki < 4; ++ki) av[ki] = *(const bf8s*)(arow + ki * 32);

  {
    int r = tid >> 1, half = tid & 1;
    const short* src = W + (size_t)(nbase + r) * 128 + half * 64;
    short* dst = &Wl[r * 144 + half * 64];
    #pragma unroll
    for (int j = 0; j < 8; ++j)
      *(bf8s*)(dst + j * 8) = *(const bf8s*)(src + j * 8);
  }
  __syncthreads();

  f32x4 acc[8] = {};
  #pragma unroll
  for (int ki = 0; ki < 4; ++ki)
    #pragma unroll
    for (int ot = 0; ot < 8; ++ot) {
      bf8s b = *(const bf8s*)(&Wl[(ot * 16 + row16) * 144 + ki * 32 + quad * 8]);
      acc[ot] = MFMA16(av[ki], b, acc[ot]);
    }

  const float* bp = (blockIdx.y == 0) ? b0 : ((blockIdx.y == 1) ? b1 : b2);
  float osc = (blockIdx.y == 0) ? 0.125f : 1.0f;  // fold 1/sqrt(64) into Q
  int m0 = tok0 + quad * 4;
  #pragma unroll
  for (int ot = 0; ot < 8; ++ot) {
    int col = ot * 16 + row16;
    float bi = bp[col];
    #pragma unroll
    for (int r = 0; r < 4; ++r) {
      float v = (acc[ot][r] + bi) * osc;
      outb[(size_t)(m0 + r) * 384 + nbase + col] = f2bf(v);
    }
  }
}

// ---------------- fused AO+LN1+FF1+FF2+LN2 [+ next-layer QKV] ----------------
// 512 threads / 128 tokens (grid 512 = exactly 2 blocks/CU).
// Round-14 law: 512-thr blocks get allocator-chosen 64-128 VGPR; NO attribute
// raises it. Fix spill by fitting 64: FF1 is SEQUENTIALIZED one 16x16 tile at a
// time (compute 4 MFMAs -> bias+relu -> stash -> next), cutting peak hacc
// liveness 16->4 regs. Phase-B peak: av16 + acc2 32 + hacc4 + addr ~ 58 < 64.
// The serialized MFMA chain (~32cyc/tile) hides behind 15 other waves.
// LDS: phase A Wa 128x144=18432sh | FF: SWi 64x144=9216 + SWf 128x80=10240 +
// stash 8x16x80=10240 = 29696sh (59392 B) -> 2 blocks/CU.
template <int DOQKV>
__global__ __launch_bounds__(512, 2) void k_aoff(
    const short* __restrict__ cb, const short* __restrict__ Wa,
    const float* __restrict__ aob, const float* __restrict__ ln1g,
    const float* __restrict__ ln1b, const short* __restrict__ Wi,
    const short* __restrict__ Wf, const float* __restrict__ ib,
    const float* __restrict__ fb, const float* __restrict__ ln2g,
    const float* __restrict__ ln2b, short* xb,
    const short* __restrict__ Wqkv2, const float* __restrict__ qb2,
    const float* __restrict__ kb2, const float* __restrict__ vb2,
    short* qkvout) {
  __shared__ short SM[29696];
  int tid = threadIdx.x, lane = tid & 63, wave = tid >> 6;
  int row16 = lane & 15, quad = lane >> 4;
  int tok0 = blockIdx.x * 128 + wave * 16;
  int m0 = tok0 + quad * 4;

  // ---- phase A: AO linear ----
  const short* arow = cb + (size_t)(tok0 + row16) * 128 + quad * 8;
  bf8s av[4];
  #pragma unroll
  for (int ki = 0; ki < 4; ++ki) av[ki] = *(const bf8s*)(arow + ki * 32);

  {  // stage Wa 128x128 (stride 144): 4 threads/row, 32 shorts each
    int r = tid >> 2, q4 = tid & 3;
    const short* src = Wa + (size_t)r * 128 + q4 * 32;
    short* dst = &SM[r * 144 + q4 * 32];
    #pragma unroll
    for (int j = 0; j < 4; ++j)
      *(bf8s*)(dst + j * 8) = *(const bf8s*)(src + j * 8);
  }
  __syncthreads();

  f32x4 acc[8] = {};
  #pragma unroll
  for (int ki = 0; ki < 4; ++ki)
    #pragma unroll
    for (int ot = 0; ot < 8; ++ot) {
      bf8s b = *(const bf8s*)(&SM[(ot * 16 + row16) * 144 + ki * 32 + quad * 8]);
      acc[ot] = MFMA16(av[ki], b, acc[ot]);
    }

  // AO epilogue: bias + residual + LN1 -> x'
  {
    float sum[4] = {}, ssq[4] = {};
    #pragma unroll
    for (int ot = 0; ot < 8; ++ot) {
      int col = ot * 16 + row16;
      float bi = aob[col];
      #pragma unroll
      for (int r = 0; r < 4; ++r) {
        float v = acc[ot][r] + bi + bf2f(xb[(size_t)(m0 + r) * HID_ + col]);
        acc[ot][r] = v;
        sum[r] += v; ssq[r] += v * v;
      }
    }
    #pragma unroll
    for (int m = 1; m <= 8; m <<= 1)
      #pragma unroll
      for (int r = 0; r < 4; ++r) {
        sum[r] += __shfl_xor(sum[r], m);
        ssq[r] += __shfl_xor(ssq[r], m);
      }
    float mean[4], rstd[4];
    #pragma unroll
    for (int r = 0; r < 4; ++r) {
      mean[r] = sum[r] / 128.f;
      float var = ssq[r] / 128.f - mean[r] * mean[r];
      rstd[r] = rsqrtf(var + 1e-5f);
    }
    #pragma unroll
    for (int ot = 0; ot < 8; ++ot) {
      int col = ot * 16 + row16;
      float gg = ln1g[col], bb2 = ln1b[col];
      #pragma unroll
      for (int r = 0; r < 4; ++r)
        acc[ot][r] = (acc[ot][r] - mean[r]) * rstd[r] * gg + bb2;  // x'
    }
  }

  // spill x' (bf16) to xb's own rows (dead until FF epilogue) -> frees acc regs
  #pragma unroll
  for (int ot = 0; ot < 8; ++ot) {
    int col = ot * 16 + row16;
    #pragma unroll
    for (int r = 0; r < 4; ++r)
      xb[(size_t)(m0 + r) * HID_ + col] = f2bf(acc[ot][r]);
  }

  // transpose x' -> A-frags through the (dead) Wa region; wave-private slice
  __syncthreads();
  {
    short* myX = &SM[wave * 2304];  // 16 rows x stride 144
    #pragma unroll
    for (int ot = 0; ot < 8; ++ot)
      #pragma unroll
      for (int r = 0; r < 4; ++r)
        myX[(quad * 4 + r) * 144 + ot * 16 + row16] = f2bf(acc[ot][r]);
    #pragma unroll
    for (int ki = 0; ki < 4; ++ki)
      av[ki] = *(const bf8s*)(myX + row16 * 144 + ki * 32 + quad * 8);
  }

  // ---- phase B: FF over 8 inter-chunks (direct global->LDS staging) ----
  int rwi = tid >> 3, q8 = tid & 7;   // Wi: 64 rows x 8 groups of 16 shorts
  int rwf = tid >> 2, qf4 = tid & 3;  // Wf: 128 rows x 4 groups of 16 shorts
  short* SWi = SM;                         // 64 x 144
  short* SWf = SM + 9216;                  // 128 x 80
  short* mySt = SM + 19456 + wave * 1280;  // 16 x 80 per wave
  f32x4 acc2[8] = {};
  for (int c = 0; c < 8; ++c) {
    __syncthreads();  // c==0: myX reads done; else: previous SWi/SWf reads done
    {  // stage Wi+Wf chunk: all 4 global loads issued before any LDS write
      const short* ws1 = Wi + (size_t)(c * 64 + rwi) * HID_ + q8 * 16;
      const short* ws2 = Wf + (size_t)rwf * 512 + c * 64 + qf4 * 16;
      bf8s a0 = *(const bf8s*)(ws1);
      bf8s a1 = *(const bf8s*)(ws1 + 8);
      bf8s b0 = *(const bf8s*)(ws2);
      bf8s b1 = *(const bf8s*)(ws2 + 8);
      short* dwi = SWi + rwi * 144 + q8 * 16;
      short* dwf = SWf + rwf * 80 + qf4 * 16;
      *(bf8s*)(dwi) = a0; *(bf8s*)(dwi + 8) = a1;
      *(bf8s*)(dwf) = b0; *(bf8s*)(dwf + 8) = b1;
    }
    __syncthreads();

    // FF1 sequentialized: one 16x16 tile at a time (peak hacc liveness = 4 regs)
    #pragma unroll
    for (int ot = 0; ot < 4; ++ot) {
      f32x4 hacc = {};
      #pragma unroll
      for (int ki = 0; ki < 4; ++ki) {
        bf8s b = *(const bf8s*)(SWi + (ot * 16 + row16) * 144 + ki * 32 + quad * 8);
        hacc = MFMA16(av[ki], b, hacc);
      }
      float bi = ib[c * 64 + ot * 16 + row16];
      #pragma unroll
      for (int r = 0; r < 4; ++r)
        mySt[(quad * 4 + r) * 80 + ot * 16 + row16] =
            f2bf(fmaxf(hacc[r] + bi, 0.f));
    }
    bf8s ha0 = *(const bf8s*)(mySt + row16 * 80 + quad * 8);
    bf8s ha1 = *(const bf8s*)(mySt + row16 * 80 + 32 + quad * 8);
    #pragma unroll
    for (int ot = 0; ot < 8; ++ot) {
      bf8s bA = *(const bf8s*)(SWf + (ot * 16 + row16) * 80 + quad * 8);
      bf8s bB = *(const bf8s*)(SWf + (ot * 16 + row16) * 80 + 32 + quad * 8);
      acc2[ot] = MFMA16(ha0, bA, acc2[ot]);
      acc2[ot] = MFMA16(ha1, bB, acc2[ot]);
    }
  }

  // FF epilogue: + fb + x'(from xb) + LN2 -> x'' in acc2; write xb
  {
    float sum[4] = {}, ssq[4] = {};
    #pragma unroll
    for (int ot = 0; ot < 8; ++ot) {
      int col = ot * 16 + row16;
      float bi = fb[col];
      #pragma unroll
      for (int r = 0; r < 4; ++r) {
        float v = acc2[ot][r] + bi + bf2f(xb[(size_t)(m0 + r) * HID_ + col]);
        acc2[ot][r] = v;
        sum[r] += v; ssq[r] += v * v;
      }
    }
    #pragma unroll
    for (int m = 1; m <= 8; m <<= 1)
      #pragma unroll
      for (int r = 0; r < 4; ++r) {
        sum[r] += __shfl_xor(sum[r], m);
        ssq[r] += __shfl_xor(ssq[r], m);
      }
    float mean[4], rstd[4];
    #pragma unroll
    for (int r = 0; r < 4; ++r) {
      mean[r] = sum[r] / 128.f;
      float var = ssq[r] / 128.f - mean[r] * mean[r];
      rstd[r] = rsqrtf(var + 1e-5f);
    }
    #pragma unroll
    for (int ot = 0; ot < 8; ++ot) {
      int col = ot * 16 + row16;
      float gg = ln2g[col], bb2 = ln2b[col];
      #pragma unroll
      for (int r = 0; r < 4; ++r) {
        float v = (acc2[ot][r] - mean[r]) * rstd[r] * gg + bb2;
        acc2[ot][r] = v;
        xb[(size_t)(m0 + r) * HID_ + col] = f2bf(v);
      }
    }
  }

  if (DOQKV) {
    // ---- tail: next-layer QKV for our own 128 tokens ----
    __syncthreads();  // all FF LDS reads done
    bf8s av2[4];
    {
      short* myX = &SM[wave * 2304];  // 16 rows x stride 144
      #pragma unroll
      for (int ot = 0; ot < 8; ++ot)
        #pragma unroll
        for (int r = 0; r < 4; ++r)
          myX[(quad * 4 + r) * 144 + ot * 16 + row16] = f2bf(acc2[ot][r]);
      #pragma unroll
      for (int ki = 0; ki < 4; ++ki)
        av2[ki] = *(const bf8s*)(myX + row16 * 144 + ki * 32 + quad * 8);
    }
    for (int c3 = 0; c3 < 3; ++c3) {
      __syncthreads();  // protects myX (c3==0) / previous chunk reads
      {  // stage Wqkv chunk 128x128 (stride 144): 4 threads/row
        int r = tid >> 2, q4 = tid & 3;
        const short* src = Wqkv2 + (size_t)(c3 * 128 + r) * 128 + q4 * 32;
        short* dst = &SM[r * 144 + q4 * 32];
        #pragma unroll
        for (int j = 0; j < 4; ++j)
          *(bf8s*)(dst + j * 8) = *(const bf8s*)(src + j * 8);
      }
      __syncthreads();
      f32x4 acc3[8] = {};
      #pragma unroll
      for (int ki = 0; ki < 4; ++ki)
        #pragma unroll
        for (int ot = 0; ot < 8; ++ot) {
          bf8s b = *(const bf8s*)(&SM[(ot * 16 + row16) * 144 + ki * 32 + quad * 8]);
          acc3[ot] = MFMA16(av2[ki], b, acc3[ot]);
        }
      const float* bp = (c3 == 0) ? qb2 : ((c3 == 1) ? kb2 : vb2);
      float osc = (c3 == 0) ? 0.125f : 1.0f;
      #pragma unroll
      for (int ot = 0; ot < 8; ++ot) {
        int col = ot * 16 + row16;
        float bi = bp[col];
        #pragma unroll
        for (int r = 0; r < 4; ++r) {
          float v = (acc3[ot][r] + bi) * osc;
          qkvout[(size_t)(m0 + r) * 384 + c3 * 128 + col] = f2bf(v);
        }
      }
    }
  }
}

// ---------------- flash attention (round-12, unchanged) ----------------
// grid = 512: blockIdx.x = (b<<2)|(h<<1)|qhalf. block = 512 (8 waves x 32 queries).
// LDS 36864 B -> 4 blocks/CU. Next stage's K/V reg-prefetched after the barrier.
// No-max softmax (Q pre-scaled; tiny scores). li per-lane, reduced in epilogue.
__global__ __launch_bounds__(512) void k_attn(const short* __restrict__ qkv,
                                              short* __restrict__ O) {
  __shared__ short Kl[64 * 72];     // 64 keys x 64 d, stride 72
  __shared__ short Vtl[64 * 72];    // 64 d x 64 keys, stride 72
  __shared__ short Pl[8][16 * 72];  // per-wave P stash (16 q x 64 k)

  int tid = threadIdx.x, lane = tid & 63, wave = tid >> 6;
  int row16 = lane & 15, quad = lane >> 4;
  int b = blockIdx.x >> 2, h = (blockIdx.x >> 1) & 1, qhalf = blockIdx.x & 1;
  const short* base  = qkv + (size_t)b * S_ * 384;
  const short* kbase = base + 128 + h * 64;
  const short* vbase = base + 256 + h * 64;
  int q0 = qhalf * 256 + wave * 32;

  bf8s qa[2][2];
  #pragma unroll
  for (int qf = 0; qf < 2; ++qf) {
    const short* qrow = base + h * 64 +
        (size_t)(q0 + qf * 16 + row16) * 384 + quad * 8;
    qa[qf][0] = *(const bf8s*)(qrow);
    qa[qf][1] = *(const bf8s*)(qrow + 32);
  }

  int krow = tid >> 3, dgk = tid & 7;
  int vkey = tid & 63, dgv = tid >> 6;
  const short* kptr = kbase + (size_t)krow * 384 + dgk * 8;
  const short* vptr = vbase + (size_t)vkey * 384 + dgv * 8;
  bf8s kst = *(const bf8s*)(kptr);
  bf8s vst = *(const bf8s*)(vptr);

  float li[2][4] = {};
  f32x4 oacc[2][4] = {};
  short* myP = &Pl[wave][0];

  for (int kt0 = 0; kt0 < S_; kt0 += 64) {
    if (kt0) __syncthreads();
    *(bf8s*)(&Kl[krow * 72 + dgk * 8]) = kst;
    #pragma unroll
    for (int j = 0; j < 8; ++j) Vtl[(dgv * 8 + j) * 72 + vkey] = vst[j];
    __syncthreads();
    if (kt0 + 64 < S_) {
      kst = *(const bf8s*)(kptr + (size_t)(kt0 + 64) * 384);
      vst = *(const bf8s*)(vptr + (size_t)(kt0 + 64) * 384);
    }

    f32x4 sc[2][4] = {};
    #pragma unroll
    for (int ks = 0; ks < 4; ++ks) {
      const short* kp = &Kl[(ks * 16 + row16) * 72 + quad * 8];
      bf8s k0 = *(const bf8s*)(kp);
      bf8s k1 = *(const bf8s*)(kp + 32);
      sc[0][ks] = MFMA16(qa[0][0], k0, sc[0][ks]);
      sc[0][ks] = MFMA16(qa[0][1], k1, sc[0][ks]);
      sc[1][ks] = MFMA16(qa[1][0], k0, sc[1][ks]);
      sc[1][ks] = MFMA16(qa[1][1], k1, sc[1][ks]);
    }

    #pragma unroll
    for (int qf = 0; qf < 2; ++qf) {
      #pragma unroll
      for (int ks = 0; ks < 4; ++ks)
        #pragma unroll
        for (int r = 0; r < 4; ++r) {
          float pv = __expf(sc[qf][ks][r]);
          li[qf][r] += pv;
          myP[(quad * 4 + r) * 72 + ks * 16 + row16] = f2bf(pv);
        }
      bf8s pa0 = *(const bf8s*)(&myP[row16 * 72 + quad * 8]);
      bf8s pa1 = *(const bf8s*)(&myP[row16 * 72 + 32 + quad * 8]);
      #pragma unroll
      for (int dt = 0; dt < 4; ++dt) {
        const short* vp = &Vtl[(dt * 16 + row16) * 72 + quad * 8];
        bf8s v0 = *(const bf8s*)(vp);
        bf8s v1 = *(const bf8s*)(vp + 32);
        oacc[qf][dt] = MFMA16(pa0, v0, oacc[qf][dt]);
        oacc[qf][dt] = MFMA16(pa1, v1, oacc[qf][dt]);
      }
    }
  }

  #pragma unroll
  for (int qf = 0; qf < 2; ++qf) {
    float inv[4];
    #pragma unroll
    for (int r = 0; r < 4; ++r) {
      float t = li[qf][r];
      #pragma unroll
      for (int m = 1; m <= 8; m <<= 1) t += __shfl_xor(t, m);
      inv[r] = 1.f / t;
    }
    size_t trow = (size_t)(b * S_ + q0 + qf * 16 + quad * 4);
    #pragma unroll
    for (int dt = 0; dt < 4; ++dt)
      #pragma unroll
      for (int r = 0; r < 4; ++r)
        O[(trow + r) * HID_ + h * 64 + dt * 16 + row16] =
            f2bf(oacc[qf][dt][r] * inv[r]);
  }
}

// ---------------- classifier ----------------
__global__ __launch_bounds__(256) void k_clf(const short* __restrict__ xb,
    const short* __restrict__ Wc, const float* __restrict__ cbias, float* out) {
  int i = threadIdx.x;  // 256 = 128 batches x 2 classes
  int b = i >> 1, c = i & 1;
  float s = 0.f;
  for (int k = 0; k < HID_; ++k)
    s += bf2f(xb[(size_t)b * S_ * HID_ + k]) * bf2f(Wc[c * HID_ + k]);
  out[b * 2 + c] = s + cbias[c];
}

// ---------------- launcher ----------------
extern "C" void kernel_launch(void* const* d_in, const int* in_sizes, int n_in,
                              void* d_out, int out_size, void* d_ws, size_t ws_size,
                              hipStream_t stream) {
  const int*   ids     = (const int*)d_in[0];
  const float* tok_emb = (const float*)d_in[1];
  const float* pos_emb = (const float*)d_in[2];
  const float* ln_g    = (const float*)d_in[3];
  const float* ln_bb   = (const float*)d_in[4];
  const float* qw      = (const float*)d_in[5];
  const float* qbias   = (const float*)d_in[6];
  const float* kw      = (const float*)d_in[7];
  const float* kbias   = (const float*)d_in[8];
  const float* vw      = (const float*)d_in[9];
  const float* vbias   = (const float*)d_in[10];
  const float* aow     = (const float*)d_in[11];
  const float* aobias  = (const float*)d_in[12];
  const float* iw      = (const float*)d_in[13];
  const float* ibias   = (const float*)d_in[14];
  const float* fow     = (const float*)d_in[15];
  const float* fbias   = (const float*)d_in[16];
  const float* ln1g    = (const float*)d_in[17];
  const float* ln1b    = (const float*)d_in[18];
  const float* ln2g    = (const float*)d_in[19];
  const float* ln2b    = (const float*)d_in[20];
  const float* clfw    = (const float*)d_in[21];
  const float* clfb    = (const float*)d_in[22];

  char* ws = (char*)d_ws;
  short* WQ  = (short*)ws;                                   // 787 KB quantized weights
  short* xb  = (short*)(ws + 1048576);                       // bf16 trunk (16.8 MB)
  short* qkv = (short*)(ws + 1048576 + 16777216);            // [tok][384] (50.3 MB)
  short* cb_ = qkv + (size_t)M_ * 384;                       // ctx [tok][128] (16.8 MB)

  k_qe<<<13 + M_ / 16, 1024, 0, stream>>>(qw, kw, vw, aow, iw, fow, clfw, WQ,
                                          ids, tok_emb, pos_emb, ln_g, ln_bb, xb);

  const short* Wqkv0 = WQ;
  const short* Wqkv1 = WQ + 49152;
  const short* Wa0   = WQ + 98304;
  const short* Wa1   = WQ + 98304 + 16384;
  const short* Wi0   = WQ + 131072;
  const short* Wi1   = WQ + 131072 + 65536;
  const short* Wf0   = WQ + 262144;
  const short* Wf1   = WQ + 262144 + 65536;

  // layer 0 (k_aoff tail computes layer-1 QKV)
  k_qkv<<<dim3(M_ / 64, 3), 256, 0, stream>>>(
      xb, Wqkv0, qbias, kbias, vbias, qkv);
  k_attn<<<512, 512, 0, stream>>>(qkv, cb_);
  k_aoff<1><<<M_ / 128, 512, 0, stream>>>(
      cb_, Wa0, aobias, ln1g, ln1b, Wi0, Wf0, ibias, fbias, ln2g, ln2b, xb,
      Wqkv1, qbias + HID_, kbias + HID_, vbias + HID_, qkv);
  // layer 1
  k_attn<<<512, 512, 0, stream>>>(qkv, cb_);
  k_aoff<0><<<M_ / 128, 512, 0, stream>>>(
      cb_, Wa1, aobias + HID_, ln1g + HID_, ln1b + HID_, Wi1, Wf1,
      ibias + 512, fbias + HID_, ln2g + HID_, ln2b + HID_, xb,
      nullptr, nullptr, nullptr, nullptr, nullptr);

  k_clf<<<1, 256, 0, stream>>>(xb, WQ + 393216, clfb, (float*)d_out);
}